// Round 2
// baseline (13023.012 us; speedup 1.0000x reference)
//
#include <hip/hip_runtime.h>
#include <math.h>

// ---- problem constants ----
#define RTOT 8192   // B*T*N token rows
#define SEQL 256    // tokens per folded sequence
#define DHC 768
#define KDC 576
#define VDC 1152
#define IMC 2048
#define NHC 12
#define DKC 48
#define DVC 96
#define NLAY 5

typedef float f4 __attribute__((ext_vector_type(4)));
typedef __bf16 v8bf __attribute__((ext_vector_type(8)));

__device__ __forceinline__ float sigmoidf_(float x){ return 1.0f/(1.0f+expf(-x)); }
__device__ __forceinline__ float siluf_(float x){ return x/(1.0f+expf(-x)); }

__device__ __forceinline__ void gl16(const void* g, void* l) {
    __builtin_amdgcn_global_load_lds((const __attribute__((address_space(1))) void*)g,
                                     (__attribute__((address_space(3))) void*)l, 16, 0, 0);
}
#define MFMA_BF16(a,b,c) __builtin_amdgcn_mfma_f32_16x16x32_bf16((a),(b),(c),0,0,0)

// =====================================================================
// bf16x3 MFMA GEMM: C[M,N] = A[M,K] @ W[N,K]^T with A,W as hi/lo bf16 planes.
// BM=BN=128, BK=32, 256 threads = 4 waves, each wave 64x64 (4x4 16x16 frags).
// mode 0: Cf = acc (+bias[col]) (+bias2[(row>>8)*ldc+col]) (+res)   [fp32]
// mode 1: Ch/Cl = hi/lo bf16 split of acc
// mode 2: v = silu(aux[idx]) * acc -> hi/lo bf16   (fused MLP gate)
// Requires M%128==0, N==ldc, N%128==0, K%32==0, planes 16B-aligned.
// =====================================================================
__global__ __launch_bounds__(256)
void gemm3_kernel(const __bf16* __restrict__ Ah, const __bf16* __restrict__ Al,
                  const __bf16* __restrict__ Wh, const __bf16* __restrict__ Wl,
                  int K, int ldc, int mode,
                  float* Cf, const float* bias, const float* bias2, const float* res,
                  __bf16* Ch, __bf16* Cl, const float* aux)
{
    __shared__ __bf16 sAh[128*32], sAl[128*32], sBh[128*32], sBl[128*32];  // 32 KB
    const int tid  = threadIdx.x;
    const int m0   = blockIdx.y * 128, n0 = blockIdx.x * 128;
    const int lane = tid & 63, wv = tid >> 6;
    const int wm   = (wv & 1) * 64, wn = (wv >> 1) * 64;

    // ---- staging geometry: LDS is linear (global_load_lds requirement);
    // swizzle lives in the GLOBAL source address (rule #21) and in reads.
    // tile elem (r,k): stored slot' = (k>>3) ^ ((r>>1)&3); byte = r*64 + slot'*16 + (k&7)*2
    const int o0 = tid * 16, o1 = o0 + 4096;         // linear LDS byte offsets
    const int r0 = o0 >> 6, s0 = (o0 >> 4) & 3;
    const int r1 = o1 >> 6, s1 = (o1 >> 4) & 3;
    const int k0 = (s0 ^ ((r0 >> 1) & 3)) * 8;       // source k-offset (elems)
    const int k1 = (s1 ^ ((r1 >> 1) & 3)) * 8;

    const __bf16* gA0h = Ah + (size_t)(m0 + r0) * K + k0;
    const __bf16* gA1h = Ah + (size_t)(m0 + r1) * K + k1;
    const __bf16* gA0l = Al + (size_t)(m0 + r0) * K + k0;
    const __bf16* gA1l = Al + (size_t)(m0 + r1) * K + k1;
    const __bf16* gB0h = Wh + (size_t)(n0 + r0) * K + k0;
    const __bf16* gB1h = Wh + (size_t)(n0 + r1) * K + k1;
    const __bf16* gB0l = Wl + (size_t)(n0 + r0) * K + k0;
    const __bf16* gB1l = Wl + (size_t)(n0 + r1) * K + k1;

    // ---- fragment LDS offsets (elements), swizzled read side
    const int fr = lane & 15, g8 = lane >> 4;
    int aoff[4], boff[4];
    #pragma unroll
    for (int f = 0; f < 4; ++f) {
        int ra = wm + f*16 + fr;
        aoff[f] = ra*32 + (g8 ^ ((ra >> 1) & 3)) * 8;
        int rb = wn + f*16 + fr;
        boff[f] = rb*32 + (g8 ^ ((rb >> 1) & 3)) * 8;
    }

    f4 acc[4][4];
    const f4 zero4 = {0.f, 0.f, 0.f, 0.f};
    #pragma unroll
    for (int i = 0; i < 4; ++i)
        #pragma unroll
        for (int j = 0; j < 4; ++j) acc[i][j] = zero4;

    for (int kt = 0; kt < K; kt += 32) {
        gl16(gA0h + kt, (char*)sAh + o0);
        gl16(gA1h + kt, (char*)sAh + o1);
        gl16(gA0l + kt, (char*)sAl + o0);
        gl16(gA1l + kt, (char*)sAl + o1);
        gl16(gB0h + kt, (char*)sBh + o0);
        gl16(gB1h + kt, (char*)sBh + o1);
        gl16(gB0l + kt, (char*)sBl + o0);
        gl16(gB1l + kt, (char*)sBl + o1);
        __syncthreads();   // drains vmcnt before any lane reads

        v8bf bhv[4], blv[4];
        #pragma unroll
        for (int f = 0; f < 4; ++f) {
            bhv[f] = *(const v8bf*)(sBh + boff[f]);
            blv[f] = *(const v8bf*)(sBl + boff[f]);
        }
        #pragma unroll
        for (int i = 0; i < 4; ++i) {
            v8bf ahv = *(const v8bf*)(sAh + aoff[i]);
            v8bf alv = *(const v8bf*)(sAl + aoff[i]);
            #pragma unroll
            for (int j = 0; j < 4; ++j) {
                f4 t = MFMA_BF16(alv, bhv[j], acc[i][j]);   // Alo*Bhi
                t    = MFMA_BF16(ahv, blv[j], t);           // Ahi*Blo
                acc[i][j] = MFMA_BF16(ahv, bhv[j], t);      // Ahi*Bhi
            }
        }
        __syncthreads();   // protect LDS from next iteration's staging
    }

    // ---- epilogue: D[row=(lane>>4)*4+j][col=lane&15] per 16x16 frag
    const int rb4 = (lane >> 4) * 4;
    #pragma unroll
    for (int i = 0; i < 4; ++i) {
        #pragma unroll
        for (int jf = 0; jf < 4; ++jf) {
            int col = n0 + wn + jf*16 + fr;
            #pragma unroll
            for (int j = 0; j < 4; ++j) {
                int row = m0 + wm + i*16 + rb4 + j;
                size_t idx = (size_t)row * ldc + col;
                float v = acc[i][jf][j];
                if (mode == 0) {
                    if (bias)  v += bias[col];
                    if (bias2) v += bias2[(size_t)(row >> 8) * ldc + col];
                    if (res)   v += res[idx];
                    Cf[idx] = v;
                } else {
                    if (mode == 2) { float a = aux[idx]; v = siluf_(a) * v; }
                    __bf16 h = (__bf16)v;
                    Ch[idx] = h;
                    Cl[idx] = (__bf16)(v - (float)h);
                }
            }
        }
    }
}

// =====================================================================
// fp32 -> (hi,lo) bf16 planes; one block per row
// =====================================================================
__global__ __launch_bounds__(256)
void cvt_hl_kernel(const float* __restrict__ src, int ld, int cols,
                   __bf16* __restrict__ dh, __bf16* __restrict__ dl)
{
    int r = blockIdx.x;
    const float* s = src + (size_t)r * ld;
    __bf16* ph = dh + (size_t)r * cols;
    __bf16* pl = dl + (size_t)r * cols;
    for (int c = threadIdx.x; c < cols; c += 256) {
        float v = s[c];
        __bf16 h = (__bf16)v;
        ph[c] = h;
        pl[c] = (__bf16)(v - (float)h);
    }
}

// =====================================================================
// fp32 fallback GEMM (round-1, proven)
// =====================================================================
__global__ __launch_bounds__(256)
void gemm_kernel(const float* __restrict__ A, const float* __restrict__ W,
                 float* C, int M, int N, int K, int ldw,
                 const float* __restrict__ bias, const float* __restrict__ bias2,
                 const float* res)
{
    __shared__ float sA[16*132];
    __shared__ float sB[16*68];
    const int tid = threadIdx.x;
    const int m0 = blockIdx.y * 128;
    const int n0 = blockIdx.x * 64;
    const int txn = tid & 15;
    const int tym = tid >> 4;

    float acc[8][4];
    #pragma unroll
    for (int i = 0; i < 8; ++i)
        #pragma unroll
        for (int j = 0; j < 4; ++j) acc[i][j] = 0.f;

    for (int kt = 0; kt < K; kt += 16) {
        #pragma unroll
        for (int i = 0; i < 8; ++i) {
            int idx = i*256 + tid;
            int r = idx >> 4, c = idx & 15;
            sA[c*132 + r] = A[(size_t)(m0 + r)*K + kt + c];
        }
        #pragma unroll
        for (int i = 0; i < 4; ++i) {
            int idx = i*256 + tid;
            int r = idx >> 4, c = idx & 15;
            sB[c*68 + r] = W[(size_t)(n0 + r)*ldw + kt + c];
        }
        __syncthreads();
        #pragma unroll
        for (int k = 0; k < 16; ++k) {
            float ar[8], br[4];
            *(float4*)&ar[0] = *(const float4*)&sA[k*132 + tym*8];
            *(float4*)&ar[4] = *(const float4*)&sA[k*132 + tym*8 + 4];
            *(float4*)&br[0] = *(const float4*)&sB[k*68 + txn*4];
            #pragma unroll
            for (int i = 0; i < 8; ++i)
                #pragma unroll
                for (int j = 0; j < 4; ++j) acc[i][j] += ar[i]*br[j];
        }
        __syncthreads();
    }

    #pragma unroll
    for (int i = 0; i < 8; ++i) {
        int row = m0 + tym*8 + i;
        #pragma unroll
        for (int j = 0; j < 4; ++j) {
            int col = n0 + txn*4 + j;
            float v = acc[i][j];
            if (bias)  v += bias[col];
            if (bias2) v += bias2[(size_t)(row >> 8)*N + col];
            if (res)   v += res[(size_t)row*N + col];
            C[(size_t)row*N + col] = v;
        }
    }
}

// =====================================================================
// encoder extra bias: B2[bt][c] = ap_b[c] + temb[t][c] + a0*ap_w[c][768] + a1*ap_w[c][769]
// =====================================================================
__global__ __launch_bounds__(256)
void bias2_kernel(const float* __restrict__ actions, const float* __restrict__ ap_w,
                  const float* __restrict__ ap_b, const float* __restrict__ temb,
                  float* __restrict__ B2)
{
    int bt = blockIdx.x;
    int t  = bt & 7;
    float a0 = actions[bt*2], a1 = actions[bt*2+1];
    for (int c = threadIdx.x; c < DHC; c += 256)
        B2[bt*DHC + c] = ap_b[c] + temb[t*DHC + c] + a0*ap_w[c*770 + 768] + a1*ap_w[c*770 + 769];
}

// =====================================================================
// RMSNorm: optional fp32 out + optional hi/lo bf16 planes
// =====================================================================
__global__ __launch_bounds__(256)
void rmsnorm_kernel(const float* __restrict__ X, const float* __restrict__ w,
                    float* Yf, __bf16* Yh, __bf16* Yl)
{
    int row = blockIdx.x, tid = threadIdx.x;
    const float* xr = X + (size_t)row*DHC;
    float v0 = xr[tid], v1 = xr[tid+256], v2 = xr[tid+512];
    __shared__ float red[256];
    red[tid] = v0*v0 + v1*v1 + v2*v2;
    __syncthreads();
    for (int s = 128; s; s >>= 1) { if (tid < s) red[tid] += red[tid+s]; __syncthreads(); }
    float r = 1.0f/sqrtf(red[0]/768.0f + 1e-6f);
    float y0 = v0*r*w[tid], y1 = v1*r*w[tid+256], y2 = v2*r*w[tid+512];
    if (Yf) {
        float* yr = Yf + (size_t)row*DHC;
        yr[tid] = y0; yr[tid+256] = y1; yr[tid+512] = y2;
    }
    if (Yh) {
        __bf16* ph = Yh + (size_t)row*DHC;
        __bf16* pl = Yl + (size_t)row*DHC;
        __bf16 h0 = (__bf16)y0, h1 = (__bf16)y1, h2 = (__bf16)y2;
        ph[tid] = h0;     pl[tid]     = (__bf16)(y0 - (float)h0);
        ph[tid+256] = h1; pl[tid+256] = (__bf16)(y1 - (float)h1);
        ph[tid+512] = h2; pl[tid+512] = (__bf16)(y2 - (float)h2);
    }
}

// =====================================================================
// Final LayerNorm (eps 1e-5, affine), same output options
// =====================================================================
__global__ __launch_bounds__(256)
void layernorm_kernel(const float* __restrict__ X, const float* __restrict__ w,
                      const float* __restrict__ b, float* Yf, __bf16* Yh, __bf16* Yl)
{
    int row = blockIdx.x, tid = threadIdx.x;
    const float* xr = X + (size_t)row*DHC;
    float v0 = xr[tid], v1 = xr[tid+256], v2 = xr[tid+512];
    __shared__ float rs[256], rs2[256];
    rs[tid]  = v0+v1+v2;
    rs2[tid] = v0*v0+v1*v1+v2*v2;
    __syncthreads();
    for (int s = 128; s; s >>= 1) { if (tid < s) { rs[tid]+=rs[tid+s]; rs2[tid]+=rs2[tid+s]; } __syncthreads(); }
    float mu  = rs[0]/768.0f;
    float var = rs2[0]/768.0f - mu*mu;
    float r = 1.0f/sqrtf(var + 1e-5f);
    float y0 = (v0-mu)*r*w[tid]     + b[tid];
    float y1 = (v1-mu)*r*w[tid+256] + b[tid+256];
    float y2 = (v2-mu)*r*w[tid+512] + b[tid+512];
    if (Yf) {
        float* yr = Yf + (size_t)row*DHC;
        yr[tid] = y0; yr[tid+256] = y1; yr[tid+512] = y2;
    }
    if (Yh) {
        __bf16* ph = Yh + (size_t)row*DHC;
        __bf16* pl = Yl + (size_t)row*DHC;
        __bf16 h0 = (__bf16)y0, h1 = (__bf16)y1, h2 = (__bf16)y2;
        ph[tid] = h0;     pl[tid]     = (__bf16)(y0 - (float)h0);
        ph[tid+256] = h1; pl[tid+256] = (__bf16)(y1 - (float)h1);
        ph[tid+512] = h2; pl[tid+512] = (__bf16)(y2 - (float)h2);
    }
}

// =====================================================================
// depthwise causal conv (K=4) + SiLU with src/dst leading dims
// =====================================================================
__global__ __launch_bounds__(64)
void convsilu_kernel(const float* __restrict__ P, int ldp, const float* __restrict__ cw,
                     float* __restrict__ Y, int ldd, int C)
{
    int c = blockIdx.x*64 + threadIdx.x;
    int r = blockIdx.y;
    int t = r & (SEQL-1);
    float acc = P[(size_t)r*ldp + c] * cw[c*4+3];
    if (t >= 1) acc += P[(size_t)(r-1)*ldp + c] * cw[c*4+2];
    if (t >= 2) acc += P[(size_t)(r-2)*ldp + c] * cw[c*4+1];
    if (t >= 3) acc += P[(size_t)(r-3)*ldp + c] * cw[c*4+0];
    Y[(size_t)r*ldd + c] = siluf_(acc);
}

// =====================================================================
// per-head L2 norm over DK=48 in place (* scale), plane stride 576
// =====================================================================
__global__ __launch_bounds__(128)
void l2norm_kernel(float* __restrict__ X, float scale)
{
    int row = blockIdx.x;
    int wave = threadIdx.x >> 6, lane = threadIdx.x & 63;
    #pragma unroll
    for (int i = 0; i < 6; ++i) {
        int h = wave*6 + i;
        size_t base = (size_t)row*KDC + h*DKC;
        float v = (lane < DKC) ? X[base + lane] : 0.f;
        float ss = v*v;
        for (int off = 32; off; off >>= 1) ss += __shfl_down(ss, off);
        ss = __shfl(ss, 0);
        float r = scale / sqrtf(ss + 1e-6f);
        if (lane < DKC) X[base + lane] = v*r;
    }
}

// =====================================================================
// beta / decay projections (reads fp32 XN)
// =====================================================================
__global__ __launch_bounds__(256)
void betag_kernel(const float* __restrict__ XN, const float* __restrict__ wb,
                  const float* __restrict__ wa, const float* __restrict__ Alog,
                  const float* __restrict__ dtb, float* __restrict__ Beta,
                  float* __restrict__ Dec)
{
    int row = blockIdx.x, tid = threadIdx.x;
    __shared__ float sx[DHC];
    for (int i = tid; i < DHC; i += 256) sx[i] = XN[(size_t)row*DHC + i];
    __syncthreads();
    int wave = tid >> 6, lane = tid & 63;
    for (int d = 0; d < 6; ++d) {
        int out = wave*6 + d;
        const float* wr = (out < NHC) ? (wb + out*DHC) : (wa + (out-NHC)*DHC);
        float acc = 0.f;
        for (int j = lane; j < DHC; j += 64) acc += sx[j]*wr[j];
        for (int off = 32; off; off >>= 1) acc += __shfl_down(acc, off);
        if (lane == 0) {
            if (out < NHC) {
                Beta[(size_t)row*NHC + out] = sigmoidf_(acc);
            } else {
                int h = out - NHC;
                float sp = acc + dtb[h];
                sp = (sp > 20.f) ? sp : log1pf(expf(sp));
                Dec[(size_t)row*NHC + h] = expf(-expf(Alog[h]) * sp);
            }
        }
    }
}

// =====================================================================
// gated delta-rule scan (S in registers, 1 block per (seq,head))
// =====================================================================
__global__ __launch_bounds__(384)
void scan_kernel(const float* __restrict__ Q, const float* __restrict__ Kk,
                 const float* __restrict__ V, const float* __restrict__ Beta,
                 const float* __restrict__ Dec, float* __restrict__ O)
{
    int bid = blockIdx.x;
    int seq = bid / NHC, h = bid % NHC;
    int tid = threadIdx.x;
    int vc = tid >> 2, rg = tid & 3;
    __shared__ float sk[DKC], sq[DKC], sv[DVC], ssc[2];

    float S[12];
    #pragma unroll
    for (int i = 0; i < 12; ++i) S[i] = 0.f;

    const float* qp = Q   + (size_t)seq*SEQL*KDC + h*DKC;
    const float* kp = Kk  + (size_t)seq*SEQL*KDC + h*DKC;
    const float* vp = V   + (size_t)seq*SEQL*VDC + h*DVC;
    const float* bp = Beta+ (size_t)seq*SEQL*NHC + h;
    const float* dp = Dec + (size_t)seq*SEQL*NHC + h;
    float* op       = O   + (size_t)seq*SEQL*VDC + h*DVC;

    for (int t = 0; t < SEQL; ++t) {
        if (tid < DKC)            sk[tid]        = kp[t*KDC + tid];
        else if (tid < 2*DKC)     sq[tid-DKC]    = qp[t*KDC + tid - DKC];
        else if (tid < 2*DKC+DVC) sv[tid-2*DKC]  = vp[t*VDC + tid - 2*DKC];
        else if (tid == 200)      ssc[0] = dp[t*NHC];
        else if (tid == 201)      ssc[1] = bp[t*NHC];
        __syncthreads();
        float dec = ssc[0], beta = ssc[1];
        float pv = 0.f;
        #pragma unroll
        for (int i = 0; i < 12; ++i) { S[i] *= dec; pv += sk[rg*12+i]*S[i]; }
        pv += __shfl_xor(pv, 1); pv += __shfl_xor(pv, 2);
        float dvv = beta * (sv[vc] - pv);
        float po = 0.f;
        #pragma unroll
        for (int i = 0; i < 12; ++i) { S[i] += sk[rg*12+i]*dvv; po += sq[rg*12+i]*S[i]; }
        po += __shfl_xor(po, 1); po += __shfl_xor(po, 2);
        if (rg == 0) op[t*VDC + vc] = po;
        __syncthreads();
    }
}

// =====================================================================
// o post: rms(O)*onorm * gate*sigmoid(gate); out fp32 and/or bf16 hi/lo
// =====================================================================
__global__ __launch_bounds__(128)
void opost_kernel(const float* O, const float* __restrict__ G, int ldg,
                  const float* __restrict__ onorm, float* Of, __bf16* Oh, __bf16* Ol)
{
    int row = blockIdx.x;
    int wave = threadIdx.x >> 6, lane = threadIdx.x & 63;
    #pragma unroll
    for (int i = 0; i < 6; ++i) {
        int h = wave*6 + i;
        size_t baseO = (size_t)row*VDC + h*DVC;
        size_t baseG = (size_t)row*ldg + h*DVC;
        float a = O[baseO + lane];
        float c = (lane < 32) ? O[baseO + 64 + lane] : 0.f;
        float ss = a*a + c*c;
        for (int off = 32; off; off >>= 1) ss += __shfl_down(ss, off);
        ss = __shfl(ss, 0);
        float r = 1.0f/sqrtf(ss/96.0f + 1e-6f);
        float ga = G[baseG + lane];
        float v0 = a*r*onorm[lane]*ga*sigmoidf_(ga);
        if (Of) Of[baseO + lane] = v0;
        if (Oh) { __bf16 hh = (__bf16)v0; Oh[baseO+lane] = hh; Ol[baseO+lane] = (__bf16)(v0 - (float)hh); }
        if (lane < 32) {
            float gb = G[baseG + 64 + lane];
            float v1 = c*r*onorm[64+lane]*gb*sigmoidf_(gb);
            if (Of) Of[baseO + 64 + lane] = v1;
            if (Oh) { __bf16 hh = (__bf16)v1; Oh[baseO+64+lane] = hh; Ol[baseO+64+lane] = (__bf16)(v1 - (float)hh); }
        }
    }
}

// =====================================================================
// fallback: y = silu(a1)*a3 into a1
// =====================================================================
__global__ __launch_bounds__(256)
void silumul_kernel(float* __restrict__ A1, const float* __restrict__ A3)
{
    size_t i = (size_t)blockIdx.x*256 + threadIdx.x;
    float4 a = ((const float4*)A1)[i];
    float4 b = ((const float4*)A3)[i];
    a.x = siluf_(a.x)*b.x; a.y = siluf_(a.y)*b.y;
    a.z = siluf_(a.z)*b.z; a.w = siluf_(a.w)*b.w;
    ((float4*)A1)[i] = a;
}

// =====================================================================
static inline void gemm_f32(const float* A, const float* W, float* C, int M, int N, int K,
                            int ldw, const float* bias, const float* bias2, const float* res,
                            hipStream_t s)
{
    dim3 grid(N/64, M/128);
    hipLaunchKernelGGL(gemm_kernel, grid, dim3(256), 0, s, A, W, C, M, N, K, ldw, bias, bias2, res);
}

static inline void gemm3(const __bf16* Ah, const __bf16* Al, const __bf16* Wh, const __bf16* Wl,
                         int K, int ldc, int mode, float* Cf, const float* bias,
                         const float* bias2, const float* res, __bf16* Ch, __bf16* Cl,
                         const float* aux, hipStream_t s)
{
    dim3 grid(ldc/128, RTOT/128);
    hipLaunchKernelGGL(gemm3_kernel, grid, dim3(256), 0, s, Ah, Al, Wh, Wl, K, ldc, mode,
                       Cf, bias, bias2, res, Ch, Cl, aux);
}

static inline void cvt(const float* src, int ld, int rows, int cols, __bf16* dh, __bf16* dl,
                       hipStream_t s)
{
    hipLaunchKernelGGL(cvt_hl_kernel, dim3(rows), dim3(256), 0, s, src, ld, cols, dh, dl);
}

extern "C" void kernel_launch(void* const* d_in, const int* in_sizes, int n_in,
                              void* d_out, int out_size, void* d_ws, size_t ws_size,
                              hipStream_t stream)
{
    const float* z       = (const float*)d_in[0];
    const float* actions = (const float*)d_in[1];
    const float* enc_w   = (const float*)d_in[2];
    const float* enc_b   = (const float*)d_in[3];
    const float* ap_w    = (const float*)d_in[4];
    const float* ap_b    = (const float*)d_in[5];
    const float* temb    = (const float*)d_in[6];
    const float* ln_w    = (const float*)d_in[7];
    const float* ln_b    = (const float*)d_in[8];
    const float* dec_w   = (const float*)d_in[9];
    const float* dec_b   = (const float*)d_in[10];
    const float* n1      = (const float*)d_in[11];
    const float* n2      = (const float*)d_in[12];
    const float* wq      = (const float*)d_in[13];
    const float* cq      = (const float*)d_in[14];
    const float* wk      = (const float*)d_in[15];
    const float* ck      = (const float*)d_in[16];
    const float* wv      = (const float*)d_in[17];
    const float* cv      = (const float*)d_in[18];
    const float* wb      = (const float*)d_in[19];
    const float* wa      = (const float*)d_in[20];
    const float* A_log   = (const float*)d_in[21];
    const float* dt_bias = (const float*)d_in[22];
    const float* wg      = (const float*)d_in[23];
    const float* onorm   = (const float*)d_in[24];
    const float* wo      = (const float*)d_in[25];
    const float* w1      = (const float*)d_in[26];
    const float* w2      = (const float*)d_in[27];
    const float* w3      = (const float*)d_in[28];

    const size_t R = RTOT;
    const float qscale = 0.14433756729740643f;   // 48^-0.5

    // ---- bf16 path workspace requirement ----
    const size_t f32_elems = (size_t)(768+768+3456+576+576+1152+1152+12+12)*R + 32*768;
    const size_t WPL = (size_t)3456*768 + 768*1152 + 3*(size_t)2048*768;      // per-layer weight elems
    const size_t wts_elems = (size_t)768*1024 + 768*768 + 1024*768 + NLAY*WPL;
    const size_t bfa_elems = (size_t)(768*2 + 1152*2 + 2048*2)*R;
    const size_t need = f32_elems*4 + (bfa_elems + 2*wts_elems)*2;

    if (ws_size >= need) {
        // ================== bf16x3 MFMA path ==================
        float* X    = (float*)d_ws;            // 768R
        float* XN   = X    + 768*R;            // 768R (fp32, for betag)
        float* BIG  = XN   + 768*R;            // 3456R: qkvg out; reused as a1f (ldc 2048)
        float* Qp   = BIG  + 3456*R;           // 576R
        float* Kp   = Qp   + 576*R;            // 576R
        float* Vp   = Kp   + 576*R;            // 1152R
        float* O    = Vp   + 1152*R;           // 1152R
        float* BETA = O    + 1152*R;           // 12R
        float* DEC  = BETA + 12*R;             // 12R
        float* TMP  = DEC  + 12*R;             // 32*768

        __bf16* bb  = (__bf16*)(TMP + 32*768);
        __bf16* XNh = bb;                      // 768R
        __bf16* XNl = XNh + 768*R;
        __bf16* Oh  = XNl + 768*R;             // 1152R
        __bf16* Ol  = Oh  + 1152*R;
        __bf16* A1h = Ol  + 1152*R;            // 2048R (aliases zh)
        __bf16* A1l = A1h + 2048*R;            // 2048R (aliases zl)
        __bf16* wp  = A1l + 2048*R;            // weight planes

        __bf16* ench = wp;                __bf16* encl = ench + (size_t)768*1024;
        __bf16* aph  = encl + (size_t)768*1024;  __bf16* apl = aph + (size_t)768*768;
        __bf16* dech = apl  + (size_t)768*768;   __bf16* decl = dech + (size_t)1024*768;
        __bf16* lw   = decl + (size_t)1024*768;  // per-layer: qkvg h,l | wo h,l | w1 h,l | w3 h,l | w2 h,l

        __bf16* zh = A1h; __bf16* zl = A1l;   // alias (encoder runs before any MLP)

        // ---- weight + z conversion ----
        cvt(z,     1024, RTOT, 1024, zh,   zl,   stream);
        cvt(enc_w, 1024, 768,  1024, ench, encl, stream);
        cvt(ap_w,  770,  768,  768,  aph,  apl,  stream);
        cvt(dec_w, 768,  1024, 768,  dech, decl, stream);
        for (int l = 0; l < NLAY; ++l) {
            __bf16* base = lw + (size_t)l * (2*WPL);
            __bf16* qkvgh = base;                         __bf16* qkvgl = qkvgh + (size_t)3456*768;
            __bf16* woh   = qkvgl + (size_t)3456*768;     __bf16* wol   = woh + (size_t)768*1152;
            __bf16* w1h   = wol   + (size_t)768*1152;     __bf16* w1l   = w1h + (size_t)2048*768;
            __bf16* w3h   = w1l   + (size_t)2048*768;     __bf16* w3l   = w3h + (size_t)2048*768;
            __bf16* w2h   = w3l   + (size_t)2048*768;     __bf16* w2l   = w2h + (size_t)768*2048;
            cvt(wq + (size_t)l*KDC*DHC, 768, 576,  768,  qkvgh,                    qkvgl,                    stream);
            cvt(wk + (size_t)l*KDC*DHC, 768, 576,  768,  qkvgh + (size_t)576*768,  qkvgl + (size_t)576*768,  stream);
            cvt(wv + (size_t)l*VDC*DHC, 768, 1152, 768,  qkvgh + (size_t)1152*768, qkvgl + (size_t)1152*768, stream);
            cvt(wg + (size_t)l*VDC*DHC, 768, 1152, 768,  qkvgh + (size_t)2304*768, qkvgl + (size_t)2304*768, stream);
            cvt(wo + (size_t)l*DHC*VDC, 1152, 768, 1152, woh, wol, stream);
            cvt(w1 + (size_t)l*IMC*DHC, 768, 2048, 768,  w1h, w1l, stream);
            cvt(w3 + (size_t)l*IMC*DHC, 768, 2048, 768,  w3h, w3l, stream);
            cvt(w2 + (size_t)l*DHC*IMC, 2048, 768, 2048, w2h, w2l, stream);
        }

        // ---- encoder ----
        hipLaunchKernelGGL(bias2_kernel, dim3(32), dim3(256), 0, stream, actions, ap_w, ap_b, temb, TMP);
        gemm3(zh, zl, ench, encl, 1024, 768, 1, nullptr, enc_b, nullptr, nullptr, XNh, XNl, nullptr, stream); // feat -> XNh/XNl
        gemm3(XNh, XNl, aph, apl, 768, 768, 0, X, nullptr, TMP, nullptr, nullptr, nullptr, nullptr, stream);  // X = tok

        // ---- layers ----
        for (int l = 0; l < NLAY; ++l) {
            __bf16* base = lw + (size_t)l * (2*WPL);
            __bf16* qkvgh = base;                         __bf16* qkvgl = qkvgh + (size_t)3456*768;
            __bf16* woh   = qkvgl + (size_t)3456*768;     __bf16* wol   = woh + (size_t)768*1152;
            __bf16* w1h   = wol   + (size_t)768*1152;     __bf16* w1l   = w1h + (size_t)2048*768;
            __bf16* w3h   = w1l   + (size_t)2048*768;     __bf16* w3l   = w3h + (size_t)2048*768;
            __bf16* w2h   = w3l   + (size_t)2048*768;     __bf16* w2l   = w2h + (size_t)768*2048;

            hipLaunchKernelGGL(rmsnorm_kernel, dim3(RTOT), dim3(256), 0, stream, X, n1 + l*DHC, XN, XNh, XNl);
            gemm3(XNh, XNl, qkvgh, qkvgl, 768, 3456, 0, BIG, nullptr, nullptr, nullptr, nullptr, nullptr, nullptr, stream);
            hipLaunchKernelGGL(betag_kernel, dim3(RTOT), dim3(256), 0, stream,
                               XN, wb + (size_t)l*NHC*DHC, wa + (size_t)l*NHC*DHC,
                               A_log + l*NHC, dt_bias + l*NHC, BETA, DEC);

            hipLaunchKernelGGL(convsilu_kernel, dim3(KDC/64, RTOT), dim3(64), 0, stream, BIG,        3456, cq + (size_t)l*KDC*4, Qp, KDC, KDC);
            hipLaunchKernelGGL(convsilu_kernel, dim3(KDC/64, RTOT), dim3(64), 0, stream, BIG + 576,  3456, ck + (size_t)l*KDC*4, Kp, KDC, KDC);
            hipLaunchKernelGGL(convsilu_kernel, dim3(VDC/64, RTOT), dim3(64), 0, stream, BIG + 1152, 3456, cv + (size_t)l*VDC*4, Vp, VDC, VDC);
            hipLaunchKernelGGL(l2norm_kernel, dim3(RTOT), dim3(128), 0, stream, Qp, qscale);
            hipLaunchKernelGGL(l2norm_kernel, dim3(RTOT), dim3(128), 0, stream, Kp, 1.0f);

            hipLaunchKernelGGL(scan_kernel, dim3(32*NHC), dim3(384), 0, stream, Qp, Kp, Vp, BETA, DEC, O);

            hipLaunchKernelGGL(opost_kernel, dim3(RTOT), dim3(128), 0, stream, O, BIG + 2304, 3456,
                               onorm + l*DVC, (float*)nullptr, Oh, Ol);
            gemm3(Oh, Ol, woh, wol, 1152, 768, 0, X, nullptr, nullptr, X, nullptr, nullptr, nullptr, stream);

            hipLaunchKernelGGL(rmsnorm_kernel, dim3(RTOT), dim3(256), 0, stream, X, n2 + l*DHC, (float*)nullptr, XNh, XNl);
            gemm3(XNh, XNl, w1h, w1l, 768, 2048, 0, BIG, nullptr, nullptr, nullptr, nullptr, nullptr, nullptr, stream); // a1f
            gemm3(XNh, XNl, w3h, w3l, 768, 2048, 2, nullptr, nullptr, nullptr, nullptr, A1h, A1l, BIG, stream);         // silu(a1)*a3
            gemm3(A1h, A1l, w2h, w2l, 2048, 768, 0, X, nullptr, nullptr, X, nullptr, nullptr, nullptr, stream);
        }

        hipLaunchKernelGGL(layernorm_kernel, dim3(RTOT), dim3(256), 0, stream, X, ln_w, ln_b, (float*)nullptr, XNh, XNl);
        gemm3(XNh, XNl, dech, decl, 768, 1024, 0, (float*)d_out, dec_b, nullptr, z, nullptr, nullptr, nullptr, stream);
        return;
    }

    // ================== fp32 fallback path (round-1, proven) ==================
    float* X    = (float*)d_ws;
    float* XN   = X    + 768*R;
    float* PRE  = XN   + 768*R;            // 2304R
    float* QKV  = PRE  + 2304*R;           // 2304R
    float* GATE = QKV  + 2304*R;           // 1152R
    float* BETA = GATE + 1152*R;
    float* DEC  = BETA + 12*R;
    float* TMP  = DEC  + 12*R;

    gemm_f32(z, enc_w, XN, RTOT, DHC, 1024, 1024, enc_b, nullptr, nullptr, stream);
    hipLaunchKernelGGL(bias2_kernel, dim3(32), dim3(256), 0, stream, actions, ap_w, ap_b, temb, TMP);
    gemm_f32(XN, ap_w, X, RTOT, DHC, DHC, 770, nullptr, TMP, nullptr, stream);

    for (int l = 0; l < NLAY; ++l) {
        const float* pwq = wq + (size_t)l*KDC*DHC;
        const float* pwk = wk + (size_t)l*KDC*DHC;
        const float* pwv = wv + (size_t)l*VDC*DHC;
        const float* pwg = wg + (size_t)l*VDC*DHC;
        const float* pwo = wo + (size_t)l*DHC*VDC;
        const float* pw1 = w1 + (size_t)l*IMC*DHC;
        const float* pw2 = w2 + (size_t)l*DHC*IMC;
        const float* pw3 = w3 + (size_t)l*IMC*DHC;

        hipLaunchKernelGGL(rmsnorm_kernel, dim3(RTOT), dim3(256), 0, stream, X, n1 + l*DHC, XN, (__bf16*)nullptr, (__bf16*)nullptr);

        gemm_f32(XN, pwq, PRE,           RTOT, KDC, DHC, DHC, nullptr, nullptr, nullptr, stream);
        gemm_f32(XN, pwk, PRE + 576*R,   RTOT, KDC, DHC, DHC, nullptr, nullptr, nullptr, stream);
        gemm_f32(XN, pwv, PRE + 1152*R,  RTOT, VDC, DHC, DHC, nullptr, nullptr, nullptr, stream);
        gemm_f32(XN, pwg, GATE,          RTOT, VDC, DHC, DHC, nullptr, nullptr, nullptr, stream);
        hipLaunchKernelGGL(betag_kernel, dim3(RTOT), dim3(256), 0, stream,
                           XN, wb + (size_t)l*NHC*DHC, wa + (size_t)l*NHC*DHC,
                           A_log + l*NHC, dt_bias + l*NHC, BETA, DEC);

        hipLaunchKernelGGL(convsilu_kernel, dim3(KDC/64, RTOT), dim3(64), 0, stream, PRE,          KDC, cq + (size_t)l*KDC*4, QKV,          KDC, KDC);
        hipLaunchKernelGGL(convsilu_kernel, dim3(KDC/64, RTOT), dim3(64), 0, stream, PRE + 576*R,  KDC, ck + (size_t)l*KDC*4, QKV + 576*R,  KDC, KDC);
        hipLaunchKernelGGL(convsilu_kernel, dim3(VDC/64, RTOT), dim3(64), 0, stream, PRE + 1152*R, VDC, cv + (size_t)l*VDC*4, QKV + 1152*R, VDC, VDC);

        hipLaunchKernelGGL(l2norm_kernel, dim3(RTOT), dim3(128), 0, stream, QKV,          qscale);
        hipLaunchKernelGGL(l2norm_kernel, dim3(RTOT), dim3(128), 0, stream, QKV + 576*R,  1.0f);

        float* O = PRE + 1152*R;
        hipLaunchKernelGGL(scan_kernel, dim3(32*NHC), dim3(384), 0, stream,
                           QKV, QKV + 576*R, QKV + 1152*R, BETA, DEC, O);

        hipLaunchKernelGGL(opost_kernel, dim3(RTOT), dim3(128), 0, stream, O, GATE, VDC,
                           onorm + l*DVC, O, (__bf16*)nullptr, (__bf16*)nullptr);
        gemm_f32(O, pwo, X, RTOT, DHC, VDC, VDC, nullptr, nullptr, X, stream);

        hipLaunchKernelGGL(rmsnorm_kernel, dim3(RTOT), dim3(256), 0, stream, X, n2 + l*DHC, XN, (__bf16*)nullptr, (__bf16*)nullptr);
        float* A1 = PRE;
        float* A3 = QKV;
        gemm_f32(XN, pw1, A1, RTOT, IMC, DHC, DHC, nullptr, nullptr, nullptr, stream);
        gemm_f32(XN, pw3, A3, RTOT, IMC, DHC, DHC, nullptr, nullptr, nullptr, stream);
        hipLaunchKernelGGL(silumul_kernel, dim3((RTOT*IMC/4)/256), dim3(256), 0, stream, A1, A3);
        gemm_f32(A1, pw2, X, RTOT, DHC, IMC, IMC, nullptr, nullptr, X, stream);
    }

    hipLaunchKernelGGL(layernorm_kernel, dim3(RTOT), dim3(256), 0, stream, X, ln_w, ln_b, XN, (__bf16*)nullptr, (__bf16*)nullptr);
    gemm_f32(XN, dec_w, (float*)d_out, RTOT, 1024, DHC, DHC, dec_b, nullptr, z, stream);
}

// Round 7
// 6527.995 us; speedup vs baseline: 1.9949x; 1.9949x over previous
//
#include <hip/hip_runtime.h>
#include <math.h>

// ---- problem constants ----
#define RTOT 8192   // B*T*N token rows
#define SEQL 256    // tokens per folded sequence
#define DHC 768
#define KDC 576
#define VDC 1152
#define IMC 2048
#define NHC 12
#define DKC 48
#define DVC 96
#define NLAY 5

typedef float f4 __attribute__((ext_vector_type(4)));
typedef __bf16 v8bf __attribute__((ext_vector_type(8)));

__device__ __forceinline__ float sigmoidf_(float x){ return 1.0f/(1.0f+expf(-x)); }
__device__ __forceinline__ float siluf_(float x){ return x/(1.0f+expf(-x)); }

__device__ __forceinline__ void gl16(const void* g, void* l) {
    __builtin_amdgcn_global_load_lds((const __attribute__((address_space(1))) void*)g,
                                     (__attribute__((address_space(3))) void*)l, 16, 0, 0);
}
#define MFMA_BF16(a,b,c) __builtin_amdgcn_mfma_f32_16x16x32_bf16((a),(b),(c),0,0,0)

// =====================================================================
// bf16x3 MFMA GEMM: C[M=8192, N=ldc] = A[M,K] @ W[N,K]^T, hi/lo bf16 planes.
// BM=BN=128, BK=32, 256 threads = 4 waves, each wave 64x64 (4x4 16x16 frags).
// epilogue: v = acc (+bias[col]) (+bias2[(row>>8)*ldc+col]) (+res[idx]);
//   mode 2: v = silu(aux[idx]) * v
//   mode 0: Cf[idx] = v ;  mode 1/2: Ch/Cl[idx] = hi/lo bf16 split
// Requires N%128==0, K%32==0, 16B-aligned planes.
// =====================================================================
__global__ __launch_bounds__(256)
void gemm3_kernel(const __bf16* __restrict__ Ah, const __bf16* __restrict__ Al,
                  const __bf16* __restrict__ Wh, const __bf16* __restrict__ Wl,
                  int K, int ldc, int mode,
                  float* Cf, const float* bias, const float* bias2, const float* res,
                  __bf16* Ch, __bf16* Cl, const float* aux)
{
    __shared__ __bf16 sAh[128*32], sAl[128*32], sBh[128*32], sBl[128*32];  // 32 KB
    const int tid  = threadIdx.x;
    const int m0   = blockIdx.y * 128, n0 = blockIdx.x * 128;
    const int lane = tid & 63, wv = tid >> 6;
    const int wm   = (wv & 1) * 64, wn = (wv >> 1) * 64;

    // LDS dest is linear (global_load_lds rule); swizzle lives in the global
    // source k-offset and in the read addresses (rule #21 both-sides).
    // tile elem (r,k): stored slot' = (k>>3) ^ ((r>>1)&3); byte = r*64 + slot'*16 + (k&7)*2
    const int o0 = tid * 16, o1 = o0 + 4096;
    const int r0 = o0 >> 6, s0 = (o0 >> 4) & 3;
    const int r1 = o1 >> 6, s1 = (o1 >> 4) & 3;
    const int k0 = (s0 ^ ((r0 >> 1) & 3)) * 8;
    const int k1 = (s1 ^ ((r1 >> 1) & 3)) * 8;

    const __bf16* gA0h = Ah + (size_t)(m0 + r0) * K + k0;
    const __bf16* gA1h = Ah + (size_t)(m0 + r1) * K + k1;
    const __bf16* gA0l = Al + (size_t)(m0 + r0) * K + k0;
    const __bf16* gA1l = Al + (size_t)(m0 + r1) * K + k1;
    const __bf16* gB0h = Wh + (size_t)(n0 + r0) * K + k0;
    const __bf16* gB1h = Wh + (size_t)(n0 + r1) * K + k1;
    const __bf16* gB0l = Wl + (size_t)(n0 + r0) * K + k0;
    const __bf16* gB1l = Wl + (size_t)(n0 + r1) * K + k1;

    const int fr = lane & 15, g8 = lane >> 4;
    int aoff[4], boff[4];
    #pragma unroll
    for (int f = 0; f < 4; ++f) {
        int ra = wm + f*16 + fr;
        aoff[f] = ra*32 + (g8 ^ ((ra >> 1) & 3)) * 8;
        int rb = wn + f*16 + fr;
        boff[f] = rb*32 + (g8 ^ ((rb >> 1) & 3)) * 8;
    }

    f4 acc[4][4];
    const f4 zero4 = {0.f, 0.f, 0.f, 0.f};
    #pragma unroll
    for (int i = 0; i < 4; ++i)
        #pragma unroll
        for (int j = 0; j < 4; ++j) acc[i][j] = zero4;

    for (int kt = 0; kt < K; kt += 32) {
        gl16(gA0h + kt, (char*)sAh + o0);
        gl16(gA1h + kt, (char*)sAh + o1);
        gl16(gA0l + kt, (char*)sAl + o0);
        gl16(gA1l + kt, (char*)sAl + o1);
        gl16(gB0h + kt, (char*)sBh + o0);
        gl16(gB1h + kt, (char*)sBh + o1);
        gl16(gB0l + kt, (char*)sBl + o0);
        gl16(gB1l + kt, (char*)sBl + o1);
        __syncthreads();   // compiler drains vmcnt before s_barrier

        v8bf bhv[4], blv[4];
        #pragma unroll
        for (int f = 0; f < 4; ++f) {
            bhv[f] = *(const v8bf*)(sBh + boff[f]);
            blv[f] = *(const v8bf*)(sBl + boff[f]);
        }
        #pragma unroll
        for (int i = 0; i < 4; ++i) {
            v8bf ahv = *(const v8bf*)(sAh + aoff[i]);
            v8bf alv = *(const v8bf*)(sAl + aoff[i]);
            #pragma unroll
            for (int j = 0; j < 4; ++j) {
                f4 t = MFMA_BF16(alv, bhv[j], acc[i][j]);   // Alo*Bhi
                t    = MFMA_BF16(ahv, blv[j], t);           // Ahi*Blo
                acc[i][j] = MFMA_BF16(ahv, bhv[j], t);      // Ahi*Bhi
            }
        }
        __syncthreads();
    }

    // epilogue: D[row=(lane>>4)*4+j][col=lane&15] per frag; row<-A frag i, col<-B frag jf
    const int rb4 = (lane >> 4) * 4;
    #pragma unroll
    for (int i = 0; i < 4; ++i) {
        #pragma unroll
        for (int jf = 0; jf < 4; ++jf) {
            int col = n0 + wn + jf*16 + fr;
            #pragma unroll
            for (int j = 0; j < 4; ++j) {
                int row = m0 + wm + i*16 + rb4 + j;
                size_t idx = (size_t)row * ldc + col;
                float v = acc[i][jf][j];
                if (bias)  v += bias[col];
                if (bias2) v += bias2[(size_t)(row >> 8) * ldc + col];
                if (res)   v += res[idx];
                if (mode == 2) v = siluf_(aux[idx]) * v;
                if (mode == 0) {
                    Cf[idx] = v;
                } else {
                    __bf16 h = (__bf16)v;
                    Ch[idx] = h;
                    Cl[idx] = (__bf16)(v - (float)h);
                }
            }
        }
    }
}

// =====================================================================
// fp32 -> (hi,lo) bf16 planes; one block per row
// =====================================================================
__global__ __launch_bounds__(256)
void cvt_hl_kernel(const float* __restrict__ src, int ld, int cols,
                   __bf16* __restrict__ dh, __bf16* __restrict__ dl)
{
    int r = blockIdx.x;
    const float* s = src + (size_t)r * ld;
    __bf16* ph = dh + (size_t)r * cols;
    __bf16* pl = dl + (size_t)r * cols;
    for (int c = threadIdx.x; c < cols; c += 256) {
        float v = s[c];
        __bf16 h = (__bf16)v;
        ph[c] = h;
        pl[c] = (__bf16)(v - (float)h);
    }
}

// =====================================================================
// encoder extra bias: B2[bt][c] = ap_b[c] + temb[t][c] + a0*ap_w[c][768] + a1*ap_w[c][769]
// =====================================================================
__global__ __launch_bounds__(256)
void bias2_kernel(const float* __restrict__ actions, const float* __restrict__ ap_w,
                  const float* __restrict__ ap_b, const float* __restrict__ temb,
                  float* __restrict__ B2)
{
    int bt = blockIdx.x;
    int t  = bt & 7;
    float a0 = actions[bt*2], a1 = actions[bt*2+1];
    for (int c = threadIdx.x; c < DHC; c += 256)
        B2[bt*DHC + c] = ap_b[c] + temb[t*DHC + c] + a0*ap_w[c*770 + 768] + a1*ap_w[c*770 + 769];
}

// =====================================================================
// RMSNorm -> hi/lo bf16 planes
// =====================================================================
__global__ __launch_bounds__(256)
void rmsnorm_kernel(const float* __restrict__ X, const float* __restrict__ w,
                    __bf16* __restrict__ Yh, __bf16* __restrict__ Yl)
{
    int row = blockIdx.x, tid = threadIdx.x;
    const float* xr = X + (size_t)row*DHC;
    float v0 = xr[tid], v1 = xr[tid+256], v2 = xr[tid+512];
    __shared__ float red[256];
    red[tid] = v0*v0 + v1*v1 + v2*v2;
    __syncthreads();
    for (int s = 128; s; s >>= 1) { if (tid < s) red[tid] += red[tid+s]; __syncthreads(); }
    float r = 1.0f/sqrtf(red[0]/768.0f + 1e-6f);
    float y0 = v0*r*w[tid], y1 = v1*r*w[tid+256], y2 = v2*r*w[tid+512];
    __bf16* ph = Yh + (size_t)row*DHC;
    __bf16* pl = Yl + (size_t)row*DHC;
    __bf16 h0 = (__bf16)y0, h1 = (__bf16)y1, h2 = (__bf16)y2;
    ph[tid] = h0;     pl[tid]     = (__bf16)(y0 - (float)h0);
    ph[tid+256] = h1; pl[tid+256] = (__bf16)(y1 - (float)h1);
    ph[tid+512] = h2; pl[tid+512] = (__bf16)(y2 - (float)h2);
}

// =====================================================================
// Final LayerNorm (eps 1e-5, affine) -> hi/lo bf16 planes
// =====================================================================
__global__ __launch_bounds__(256)
void layernorm_kernel(const float* __restrict__ X, const float* __restrict__ w,
                      const float* __restrict__ b, __bf16* __restrict__ Yh,
                      __bf16* __restrict__ Yl)
{
    int row = blockIdx.x, tid = threadIdx.x;
    const float* xr = X + (size_t)row*DHC;
    float v0 = xr[tid], v1 = xr[tid+256], v2 = xr[tid+512];
    __shared__ float rs[256], rs2[256];
    rs[tid]  = v0+v1+v2;
    rs2[tid] = v0*v0+v1*v1+v2*v2;
    __syncthreads();
    for (int s = 128; s; s >>= 1) { if (tid < s) { rs[tid]+=rs[tid+s]; rs2[tid]+=rs2[tid+s]; } __syncthreads(); }
    float mu  = rs[0]/768.0f;
    float var = rs2[0]/768.0f - mu*mu;
    float r = 1.0f/sqrtf(var + 1e-5f);
    float y0 = (v0-mu)*r*w[tid]     + b[tid];
    float y1 = (v1-mu)*r*w[tid+256] + b[tid+256];
    float y2 = (v2-mu)*r*w[tid+512] + b[tid+512];
    __bf16* ph = Yh + (size_t)row*DHC;
    __bf16* pl = Yl + (size_t)row*DHC;
    __bf16 h0 = (__bf16)y0, h1 = (__bf16)y1, h2 = (__bf16)y2;
    ph[tid] = h0;     pl[tid]     = (__bf16)(y0 - (float)h0);
    ph[tid+256] = h1; pl[tid+256] = (__bf16)(y1 - (float)h1);
    ph[tid+512] = h2; pl[tid+512] = (__bf16)(y2 - (float)h2);
}

// =====================================================================
// depthwise causal conv (K=4) + SiLU; src ld ldp, dst ld ldd
// =====================================================================
__global__ __launch_bounds__(64)
void convsilu_kernel(const float* __restrict__ P, int ldp, const float* __restrict__ cw,
                     float* __restrict__ Y, int ldd, int C)
{
    int c = blockIdx.x*64 + threadIdx.x;
    if (c >= C) return;
    int r = blockIdx.y;
    int t = r & (SEQL-1);
    float acc = P[(size_t)r*ldp + c] * cw[c*4+3];
    if (t >= 1) acc += P[(size_t)(r-1)*ldp + c] * cw[c*4+2];
    if (t >= 2) acc += P[(size_t)(r-2)*ldp + c] * cw[c*4+1];
    if (t >= 3) acc += P[(size_t)(r-3)*ldp + c] * cw[c*4+0];
    Y[(size_t)r*ldd + c] = siluf_(acc);
}

// =====================================================================
// per-head L2 norm over DK=48 in place (* scale); base X + row*ld + col0
// =====================================================================
__global__ __launch_bounds__(128)
void l2norm_kernel(float* __restrict__ X, int ld, int col0, float scale)
{
    int row = blockIdx.x;
    int wave = threadIdx.x >> 6, lane = threadIdx.x & 63;
    #pragma unroll
    for (int i = 0; i < 6; ++i) {
        int h = wave*6 + i;
        size_t base = (size_t)row*ld + col0 + h*DKC;
        float v = (lane < DKC) ? X[base + lane] : 0.f;
        float ss = v*v;
        for (int off = 32; off; off >>= 1) ss += __shfl_down(ss, off);
        ss = __shfl(ss, 0);
        float r = scale / sqrtf(ss + 1e-6f);
        if (lane < DKC) X[base + lane] = v*r;
    }
}

// =====================================================================
// beta / decay projections (reads x = hi+lo bf16 planes)
// =====================================================================
__global__ __launch_bounds__(256)
void betag_kernel(const __bf16* __restrict__ XNh, const __bf16* __restrict__ XNl,
                  const float* __restrict__ wb, const float* __restrict__ wa,
                  const float* __restrict__ Alog, const float* __restrict__ dtb,
                  float* __restrict__ Beta, float* __restrict__ Dec)
{
    int row = blockIdx.x, tid = threadIdx.x;
    __shared__ float sx[DHC];
    for (int i = tid; i < DHC; i += 256)
        sx[i] = (float)XNh[(size_t)row*DHC + i] + (float)XNl[(size_t)row*DHC + i];
    __syncthreads();
    int wave = tid >> 6, lane = tid & 63;
    for (int d = 0; d < 6; ++d) {
        int out = wave*6 + d;
        const float* wr = (out < NHC) ? (wb + out*DHC) : (wa + (out-NHC)*DHC);
        float acc = 0.f;
        for (int j = lane; j < DHC; j += 64) acc += sx[j]*wr[j];
        for (int off = 32; off; off >>= 1) acc += __shfl_down(acc, off);
        if (lane == 0) {
            if (out < NHC) {
                Beta[(size_t)row*NHC + out] = sigmoidf_(acc);
            } else {
                int h = out - NHC;
                float sp = acc + dtb[h];
                sp = (sp > 20.f) ? sp : log1pf(expf(sp));
                Dec[(size_t)row*NHC + h] = expf(-expf(Alog[h]) * sp);
            }
        }
    }
}

// =====================================================================
// gated delta-rule scan; q/k/v packed in QKV[row][2304] (q|k|v)
// =====================================================================
__global__ __launch_bounds__(384)
void scan_kernel(const float* __restrict__ QKV, const float* __restrict__ Beta,
                 const float* __restrict__ Dec, float* __restrict__ O)
{
    int bid = blockIdx.x;
    int seq = bid / NHC, h = bid % NHC;
    int tid = threadIdx.x;
    int vc = tid >> 2, rg = tid & 3;
    __shared__ float sk[DKC], sq[DKC], sv[DVC], ssc[2];

    float S[12];
    #pragma unroll
    for (int i = 0; i < 12; ++i) S[i] = 0.f;

    const float* qp = QKV + (size_t)seq*SEQL*2304 + h*DKC;          // ld 2304
    const float* kp = qp + 576;
    const float* vp = QKV + (size_t)seq*SEQL*2304 + 1152 + h*DVC;
    const float* bp = Beta+ (size_t)seq*SEQL*NHC + h;
    const float* dp = Dec + (size_t)seq*SEQL*NHC + h;
    float* op       = O   + (size_t)seq*SEQL*VDC + h*DVC;

    for (int t = 0; t < SEQL; ++t) {
        if (tid < DKC)            sk[tid]        = kp[(size_t)t*2304 + tid];
        else if (tid < 2*DKC)     sq[tid-DKC]    = qp[(size_t)t*2304 + tid - DKC];
        else if (tid < 2*DKC+DVC) sv[tid-2*DKC]  = vp[(size_t)t*2304 + tid - 2*DKC];
        else if (tid == 200)      ssc[0] = dp[(size_t)t*NHC];
        else if (tid == 201)      ssc[1] = bp[(size_t)t*NHC];
        __syncthreads();
        float dec = ssc[0], beta = ssc[1];
        float pv = 0.f;
        #pragma unroll
        for (int i = 0; i < 12; ++i) { S[i] *= dec; pv += sk[rg*12+i]*S[i]; }
        pv += __shfl_xor(pv, 1); pv += __shfl_xor(pv, 2);
        float dvv = beta * (sv[vc] - pv);
        float po = 0.f;
        #pragma unroll
        for (int i = 0; i < 12; ++i) { S[i] += sk[rg*12+i]*dvv; po += sq[rg*12+i]*S[i]; }
        po += __shfl_xor(po, 1); po += __shfl_xor(po, 2);
        if (rg == 0) op[(size_t)t*VDC + vc] = po;
        __syncthreads();
    }
}

// =====================================================================
// o post: rms(O)*onorm * gate*sigmoid(gate) -> hi/lo bf16
// =====================================================================
__global__ __launch_bounds__(128)
void opost_kernel(const float* __restrict__ O, const float* __restrict__ G, int ldg,
                  const float* __restrict__ onorm, __bf16* __restrict__ Oh,
                  __bf16* __restrict__ Ol)
{
    int row = blockIdx.x;
    int wave = threadIdx.x >> 6, lane = threadIdx.x & 63;
    #pragma unroll
    for (int i = 0; i < 6; ++i) {
        int h = wave*6 + i;
        size_t baseO = (size_t)row*VDC + h*DVC;
        size_t baseG = (size_t)row*ldg + h*DVC;
        float a = O[baseO + lane];
        float c = (lane < 32) ? O[baseO + 64 + lane] : 0.f;
        float ss = a*a + c*c;
        for (int off = 32; off; off >>= 1) ss += __shfl_down(ss, off);
        ss = __shfl(ss, 0);
        float r = 1.0f/sqrtf(ss/96.0f + 1e-6f);
        float ga = G[baseG + lane];
        float v0 = a*r*onorm[lane]*ga*sigmoidf_(ga);
        { __bf16 hh = (__bf16)v0; Oh[baseO+lane] = hh; Ol[baseO+lane] = (__bf16)(v0 - (float)hh); }
        if (lane < 32) {
            float gb = G[baseG + 64 + lane];
            float v1 = c*r*onorm[64+lane]*gb*sigmoidf_(gb);
            __bf16 hh = (__bf16)v1; Oh[baseO+64+lane] = hh; Ol[baseO+64+lane] = (__bf16)(v1 - (float)hh);
        }
    }
}

// =====================================================================
static inline void gemm3(const __bf16* Ah, const __bf16* Al, const __bf16* Wh, const __bf16* Wl,
                         int K, int ldc, int mode, float* Cf, const float* bias,
                         const float* bias2, const float* res, __bf16* Ch, __bf16* Cl,
                         const float* aux, hipStream_t s)
{
    dim3 grid(ldc/128, RTOT/128);
    hipLaunchKernelGGL(gemm3_kernel, grid, dim3(256), 0, s, Ah, Al, Wh, Wl, K, ldc, mode,
                       Cf, bias, bias2, res, Ch, Cl, aux);
}

static inline void cvt(const float* src, int ld, int rows, int cols, __bf16* dh, __bf16* dl,
                       hipStream_t s)
{
    hipLaunchKernelGGL(cvt_hl_kernel, dim3(rows), dim3(256), 0, s, src, ld, cols, dh, dl);
}

extern "C" void kernel_launch(void* const* d_in, const int* in_sizes, int n_in,
                              void* d_out, int out_size, void* d_ws, size_t ws_size,
                              hipStream_t stream)
{
    const float* z       = (const float*)d_in[0];
    const float* actions = (const float*)d_in[1];
    const float* enc_w   = (const float*)d_in[2];
    const float* enc_b   = (const float*)d_in[3];
    const float* ap_w    = (const float*)d_in[4];
    const float* ap_b    = (const float*)d_in[5];
    const float* temb    = (const float*)d_in[6];
    const float* ln_w    = (const float*)d_in[7];
    const float* ln_b    = (const float*)d_in[8];
    const float* dec_w   = (const float*)d_in[9];
    const float* dec_b   = (const float*)d_in[10];
    const float* n1      = (const float*)d_in[11];
    const float* n2      = (const float*)d_in[12];
    const float* wq      = (const float*)d_in[13];
    const float* cq      = (const float*)d_in[14];
    const float* wk      = (const float*)d_in[15];
    const float* ck      = (const float*)d_in[16];
    const float* wv      = (const float*)d_in[17];
    const float* cv      = (const float*)d_in[18];
    const float* wb      = (const float*)d_in[19];
    const float* wa      = (const float*)d_in[20];
    const float* A_log   = (const float*)d_in[21];
    const float* dt_bias = (const float*)d_in[22];
    const float* wg      = (const float*)d_in[23];
    const float* onorm   = (const float*)d_in[24];
    const float* wo      = (const float*)d_in[25];
    const float* w1      = (const float*)d_in[26];
    const float* w2      = (const float*)d_in[27];
    const float* w3      = (const float*)d_in[28];

    const size_t R = RTOT;
    const float qscale = 0.14433756729740643f;   // 48^-0.5

    // ---- workspace layout (235.2 MB total; proven ws_size >= 239.96 MB) ----
    float* X    = (float*)d_ws;                  // 768R fp32: residual stream
    float* BUF1 = X    + 768*R;                  // 1152R fp32: qk-pre / v-pre / GATE; A1h alias
    float* O    = BUF1 + 1152*R;                 // 1152R fp32: scan out; A1l alias
    float* QKV  = O    + 1152*R;                 // 2304R fp32: conv out (q|k|v, ld2304); zh/zl, Oh/Ol, A1f alias
    float* BETA = QKV  + 2304*R;                 // 12R
    float* DEC  = BETA + 12*R;                   // 12R
    float* TMP  = DEC  + 12*R;                   // 32*768
    __bf16* XNh = (__bf16*)(TMP + 32*768);       // 768R
    __bf16* XNl = XNh + 768*R;                   // 768R
    __bf16* WS0 = XNl + 768*R;                   // 16,515,072 bf16 weight scratch

    const size_t need = (size_t)(768+1152+1152+2304+24)*R*4 + 32*768*4
                      + ((size_t)1536*R + 16515072)*2;
    if (ws_size < need) return;   // cannot happen: round-1 layout (239.96MB) ran

    // aliases
    __bf16* zh  = (__bf16*)QKV;                  // 1024R
    __bf16* zl  = zh + 1024*R;
    __bf16* Oh  = (__bf16*)QKV;                  // 1152R
    __bf16* Ol  = Oh + 1152*R;
    float*  A1f = QKV;                           // 2048R fp32 (ldc 2048)
    __bf16* A1h = (__bf16*)BUF1;                 // 2048R bf16 (33.5MB <= 37.7MB)
    __bf16* A1l = (__bf16*)O;                    // 2048R bf16

    // ---- encoder ----
    {
        __bf16* ench = WS0;                       __bf16* encl = ench + (size_t)768*1024;
        __bf16* aph  = encl + (size_t)768*1024;   __bf16* apl  = aph  + (size_t)768*768;
        cvt(z,     1024, RTOT, 1024, zh,   zl,   stream);
        cvt(enc_w, 1024, 768,  1024, ench, encl, stream);
        cvt(ap_w,  770,  768,  768,  aph,  apl,  stream);
        hipLaunchKernelGGL(bias2_kernel, dim3(32), dim3(256), 0, stream, actions, ap_w, ap_b, temb, TMP);
        gemm3(zh, zl, ench, encl, 1024, 768, 1, nullptr, enc_b, nullptr, nullptr, XNh, XNl, nullptr, stream);
        gemm3(XNh, XNl, aph, apl, 768, 768, 0, X, nullptr, TMP, nullptr, nullptr, nullptr, nullptr, stream);
    }

    // ---- layers ----
    for (int l = 0; l < NLAY; ++l) {
        // per-layer weight planes in shared scratch (stream-ordered reuse)
        __bf16* qkh = WS0;                        __bf16* qkl = qkh + (size_t)1152*768;
        __bf16* vh  = qkl + (size_t)1152*768;     __bf16* vl  = vh  + (size_t)1152*768;
        __bf16* gh  = vl  + (size_t)1152*768;     __bf16* gl_ = gh  + (size_t)1152*768;
        __bf16* woh = gl_ + (size_t)1152*768;     __bf16* wol = woh + (size_t)768*1152;
        __bf16* w1h = wol + (size_t)768*1152;     __bf16* w1l = w1h + (size_t)2048*768;
        __bf16* w3h = w1l + (size_t)2048*768;     __bf16* w3l = w3h + (size_t)2048*768;
        __bf16* w2h = w3l + (size_t)2048*768;     __bf16* w2l = w2h + (size_t)768*2048;

        cvt(wq + (size_t)l*KDC*DHC, 768, 576,  768,  qkh,                  qkl,                  stream);
        cvt(wk + (size_t)l*KDC*DHC, 768, 576,  768,  qkh + (size_t)576*768, qkl + (size_t)576*768, stream);
        cvt(wv + (size_t)l*VDC*DHC, 768, 1152, 768,  vh,  vl,  stream);
        cvt(wg + (size_t)l*VDC*DHC, 768, 1152, 768,  gh,  gl_, stream);
        cvt(wo + (size_t)l*DHC*VDC, 1152, 768, 1152, woh, wol, stream);
        cvt(w1 + (size_t)l*IMC*DHC, 768, 2048, 768,  w1h, w1l, stream);
        cvt(w3 + (size_t)l*IMC*DHC, 768, 2048, 768,  w3h, w3l, stream);
        cvt(w2 + (size_t)l*DHC*IMC, 2048, 768, 2048, w2h, w2l, stream);

        // attn input norm -> hi/lo planes
        hipLaunchKernelGGL(rmsnorm_kernel, dim3(RTOT), dim3(256), 0, stream, X, n1 + l*DHC, XNh, XNl);

        // qk projection -> BUF1, conv q,k -> QKV[:,0:1152]
        gemm3(XNh, XNl, qkh, qkl, 768, 1152, 0, BUF1, nullptr, nullptr, nullptr, nullptr, nullptr, nullptr, stream);
        hipLaunchKernelGGL(convsilu_kernel, dim3(9,  RTOT), dim3(64), 0, stream, BUF1,       1152, cq + (size_t)l*KDC*4, QKV,        2304, KDC);
        hipLaunchKernelGGL(convsilu_kernel, dim3(9,  RTOT), dim3(64), 0, stream, BUF1 + 576, 1152, ck + (size_t)l*KDC*4, QKV + 576,  2304, KDC);
        // v projection -> BUF1 (overwrite), conv v -> QKV[:,1152:2304]
        gemm3(XNh, XNl, vh, vl, 768, 1152, 0, BUF1, nullptr, nullptr, nullptr, nullptr, nullptr, nullptr, stream);
        hipLaunchKernelGGL(convsilu_kernel, dim3(18, RTOT), dim3(64), 0, stream, BUF1,       1152, cv + (size_t)l*VDC*4, QKV + 1152, 2304, VDC);
        // gate projection -> BUF1 = GATE
        gemm3(XNh, XNl, gh, gl_, 768, 1152, 0, BUF1, nullptr, nullptr, nullptr, nullptr, nullptr, nullptr, stream);
        // beta / decay
        hipLaunchKernelGGL(betag_kernel, dim3(RTOT), dim3(256), 0, stream,
                           XNh, XNl, wb + (size_t)l*NHC*DHC, wa + (size_t)l*NHC*DHC,
                           A_log + l*NHC, dt_bias + l*NHC, BETA, DEC);

        // l2 norm q (scaled), k
        hipLaunchKernelGGL(l2norm_kernel, dim3(RTOT), dim3(128), 0, stream, QKV, 2304, 0,   qscale);
        hipLaunchKernelGGL(l2norm_kernel, dim3(RTOT), dim3(128), 0, stream, QKV, 2304, 576, 1.0f);

        // recurrent delta-rule scan
        hipLaunchKernelGGL(scan_kernel, dim3(32*NHC), dim3(384), 0, stream, QKV, BETA, DEC, O);

        // opost -> Oh/Ol (QKV region; q/k/v dead after scan)
        hipLaunchKernelGGL(opost_kernel, dim3(RTOT), dim3(128), 0, stream, O, BUF1, 1152,
                           onorm + l*DVC, Oh, Ol);
        gemm3(Oh, Ol, woh, wol, 1152, 768, 0, X, nullptr, nullptr, X, nullptr, nullptr, nullptr, stream);

        // MLP
        hipLaunchKernelGGL(rmsnorm_kernel, dim3(RTOT), dim3(256), 0, stream, X, n2 + l*DHC, XNh, XNl);
        gemm3(XNh, XNl, w1h, w1l, 768, 2048, 0, A1f, nullptr, nullptr, nullptr, nullptr, nullptr, nullptr, stream);
        gemm3(XNh, XNl, w3h, w3l, 768, 2048, 2, nullptr, nullptr, nullptr, nullptr, A1h, A1l, A1f, stream);
        gemm3(A1h, A1l, w2h, w2l, 2048, 768, 0, X, nullptr, nullptr, X, nullptr, nullptr, nullptr, stream);
    }

    // ---- final LN + decoder + residual ----
    {
        __bf16* dech = WS0;  __bf16* decl = dech + (size_t)1024*768;
        cvt(dec_w, 768, 1024, 768, dech, decl, stream);
        hipLaunchKernelGGL(layernorm_kernel, dim3(RTOT), dim3(256), 0, stream, X, ln_w, ln_b, XNh, XNl);
        gemm3(XNh, XNl, dech, decl, 768, 1024, 0, (float*)d_out, dec_b, nullptr, z, nullptr, nullptr, nullptr, stream);
    }
}

// Round 8
// 5884.085 us; speedup vs baseline: 2.2133x; 1.1094x over previous
//
#include <hip/hip_runtime.h>
#include <math.h>

// ---- problem constants ----
#define RTOT 8192   // B*T*N token rows
#define SEQL 256    // tokens per folded sequence
#define DHC 768
#define KDC 576
#define VDC 1152
#define IMC 2048
#define NHC 12
#define DKC 48
#define DVC 96
#define NLAY 5

typedef float f4 __attribute__((ext_vector_type(4)));
typedef __bf16 v8bf __attribute__((ext_vector_type(8)));

__device__ __forceinline__ float sigmoidf_(float x){ return 1.0f/(1.0f+expf(-x)); }
__device__ __forceinline__ float siluf_(float x){ return x/(1.0f+expf(-x)); }

__device__ __forceinline__ void gl16(const void* g, void* l) {
    __builtin_amdgcn_global_load_lds((const __attribute__((address_space(1))) void*)g,
                                     (__attribute__((address_space(3))) void*)l, 16, 0, 0);
}
#define MFMA_BF16(a,b,c) __builtin_amdgcn_mfma_f32_16x16x32_bf16((a),(b),(c),0,0,0)

// =====================================================================
// bf16x3 MFMA GEMM: C[M=8192, N=ldc] = A[M,K] @ W[N,K]^T, hi/lo bf16 planes.
// BM=BN=128, BK=32, 256 threads = 4 waves, each wave 64x64 (4x4 16x16 frags).
// (proven in round 7: 12.9 -> 6.5 ms, absmax 0.03125 — DO NOT TOUCH this round)
// =====================================================================
__global__ __launch_bounds__(256)
void gemm3_kernel(const __bf16* __restrict__ Ah, const __bf16* __restrict__ Al,
                  const __bf16* __restrict__ Wh, const __bf16* __restrict__ Wl,
                  int K, int ldc, int mode,
                  float* Cf, const float* bias, const float* bias2, const float* res,
                  __bf16* Ch, __bf16* Cl, const float* aux)
{
    __shared__ __bf16 sAh[128*32], sAl[128*32], sBh[128*32], sBl[128*32];  // 32 KB
    const int tid  = threadIdx.x;
    const int m0   = blockIdx.y * 128, n0 = blockIdx.x * 128;
    const int lane = tid & 63, wv = tid >> 6;
    const int wm   = (wv & 1) * 64, wn = (wv >> 1) * 64;

    // LDS dest is linear (global_load_lds rule); swizzle lives in the global
    // source k-offset and in the read addresses (rule #21 both-sides).
    // tile elem (r,k): stored slot' = (k>>3) ^ ((r>>1)&3); byte = r*64 + slot'*16 + (k&7)*2
    const int o0 = tid * 16, o1 = o0 + 4096;
    const int r0 = o0 >> 6, s0 = (o0 >> 4) & 3;
    const int r1 = o1 >> 6, s1 = (o1 >> 4) & 3;
    const int k0 = (s0 ^ ((r0 >> 1) & 3)) * 8;
    const int k1 = (s1 ^ ((r1 >> 1) & 3)) * 8;

    const __bf16* gA0h = Ah + (size_t)(m0 + r0) * K + k0;
    const __bf16* gA1h = Ah + (size_t)(m0 + r1) * K + k1;
    const __bf16* gA0l = Al + (size_t)(m0 + r0) * K + k0;
    const __bf16* gA1l = Al + (size_t)(m0 + r1) * K + k1;
    const __bf16* gB0h = Wh + (size_t)(n0 + r0) * K + k0;
    const __bf16* gB1h = Wh + (size_t)(n0 + r1) * K + k1;
    const __bf16* gB0l = Wl + (size_t)(n0 + r0) * K + k0;
    const __bf16* gB1l = Wl + (size_t)(n0 + r1) * K + k1;

    const int fr = lane & 15, g8 = lane >> 4;
    int aoff[4], boff[4];
    #pragma unroll
    for (int f = 0; f < 4; ++f) {
        int ra = wm + f*16 + fr;
        aoff[f] = ra*32 + (g8 ^ ((ra >> 1) & 3)) * 8;
        int rb = wn + f*16 + fr;
        boff[f] = rb*32 + (g8 ^ ((rb >> 1) & 3)) * 8;
    }

    f4 acc[4][4];
    const f4 zero4 = {0.f, 0.f, 0.f, 0.f};
    #pragma unroll
    for (int i = 0; i < 4; ++i)
        #pragma unroll
        for (int j = 0; j < 4; ++j) acc[i][j] = zero4;

    for (int kt = 0; kt < K; kt += 32) {
        gl16(gA0h + kt, (char*)sAh + o0);
        gl16(gA1h + kt, (char*)sAh + o1);
        gl16(gA0l + kt, (char*)sAl + o0);
        gl16(gA1l + kt, (char*)sAl + o1);
        gl16(gB0h + kt, (char*)sBh + o0);
        gl16(gB1h + kt, (char*)sBh + o1);
        gl16(gB0l + kt, (char*)sBl + o0);
        gl16(gB1l + kt, (char*)sBl + o1);
        __syncthreads();   // compiler drains vmcnt before s_barrier

        v8bf bhv[4], blv[4];
        #pragma unroll
        for (int f = 0; f < 4; ++f) {
            bhv[f] = *(const v8bf*)(sBh + boff[f]);
            blv[f] = *(const v8bf*)(sBl + boff[f]);
        }
        #pragma unroll
        for (int i = 0; i < 4; ++i) {
            v8bf ahv = *(const v8bf*)(sAh + aoff[i]);
            v8bf alv = *(const v8bf*)(sAl + aoff[i]);
            #pragma unroll
            for (int j = 0; j < 4; ++j) {
                f4 t = MFMA_BF16(alv, bhv[j], acc[i][j]);   // Alo*Bhi
                t    = MFMA_BF16(ahv, blv[j], t);           // Ahi*Blo
                acc[i][j] = MFMA_BF16(ahv, bhv[j], t);      // Ahi*Bhi
            }
        }
        __syncthreads();
    }

    // epilogue: D[row=(lane>>4)*4+j][col=lane&15] per frag; row<-A frag i, col<-B frag jf
    const int rb4 = (lane >> 4) * 4;
    #pragma unroll
    for (int i = 0; i < 4; ++i) {
        #pragma unroll
        for (int jf = 0; jf < 4; ++jf) {
            int col = n0 + wn + jf*16 + fr;
            #pragma unroll
            for (int j = 0; j < 4; ++j) {
                int row = m0 + wm + i*16 + rb4 + j;
                size_t idx = (size_t)row * ldc + col;
                float v = acc[i][jf][j];
                if (bias)  v += bias[col];
                if (bias2) v += bias2[(size_t)(row >> 8) * ldc + col];
                if (res)   v += res[idx];
                if (mode == 2) v = siluf_(aux[idx]) * v;
                if (mode == 0) {
                    Cf[idx] = v;
                } else {
                    __bf16 h = (__bf16)v;
                    Ch[idx] = h;
                    Cl[idx] = (__bf16)(v - (float)h);
                }
            }
        }
    }
}

// =====================================================================
// batched fp32 -> (hi,lo) bf16 conversion: up to 8 jobs in one launch
// (replaces 8 tiny cvt launches per layer -> 1; removes stream gaps)
// =====================================================================
struct CvtBatch8 {
    const float* src[8];
    __bf16* dh[8];
    __bf16* dl[8];
    int ldv[8];
    int cols[8];
    int rowend[8];   // exclusive prefix sum of rows
};

__global__ __launch_bounds__(256)
void cvt_batch_kernel(CvtBatch8 b, int njobs)
{
    int r = blockIdx.x;
    int j = 0;
    while (j < njobs - 1 && r >= b.rowend[j]) ++j;   // uniform per block
    int row0 = (j == 0) ? 0 : b.rowend[j-1];
    int lr = r - row0;
    const float* s = b.src[j] + (size_t)lr * b.ldv[j];
    __bf16* ph = b.dh[j] + (size_t)lr * b.cols[j];
    __bf16* pl = b.dl[j] + (size_t)lr * b.cols[j];
    int cols = b.cols[j];
    for (int c = threadIdx.x; c < cols; c += 256) {
        float v = s[c];
        __bf16 hh = (__bf16)v;
        ph[c] = hh;
        pl[c] = (__bf16)(v - (float)hh);
    }
}

// =====================================================================
// encoder extra bias: B2[bt][c] = ap_b[c] + temb[t][c] + a0*ap_w[c][768] + a1*ap_w[c][769]
// =====================================================================
__global__ __launch_bounds__(256)
void bias2_kernel(const float* __restrict__ actions, const float* __restrict__ ap_w,
                  const float* __restrict__ ap_b, const float* __restrict__ temb,
                  float* __restrict__ B2)
{
    int bt = blockIdx.x;
    int t  = bt & 7;
    float a0 = actions[bt*2], a1 = actions[bt*2+1];
    for (int c = threadIdx.x; c < DHC; c += 256)
        B2[bt*DHC + c] = ap_b[c] + temb[t*DHC + c] + a0*ap_w[c*770 + 768] + a1*ap_w[c*770 + 769];
}

// =====================================================================
// RMSNorm -> hi/lo bf16 planes
// =====================================================================
__global__ __launch_bounds__(256)
void rmsnorm_kernel(const float* __restrict__ X, const float* __restrict__ w,
                    __bf16* __restrict__ Yh, __bf16* __restrict__ Yl)
{
    int row = blockIdx.x, tid = threadIdx.x;
    const float* xr = X + (size_t)row*DHC;
    float v0 = xr[tid], v1 = xr[tid+256], v2 = xr[tid+512];
    __shared__ float red[256];
    red[tid] = v0*v0 + v1*v1 + v2*v2;
    __syncthreads();
    for (int s = 128; s; s >>= 1) { if (tid < s) red[tid] += red[tid+s]; __syncthreads(); }
    float r = 1.0f/sqrtf(red[0]/768.0f + 1e-6f);
    float y0 = v0*r*w[tid], y1 = v1*r*w[tid+256], y2 = v2*r*w[tid+512];
    __bf16* ph = Yh + (size_t)row*DHC;
    __bf16* pl = Yl + (size_t)row*DHC;
    __bf16 h0 = (__bf16)y0, h1 = (__bf16)y1, h2 = (__bf16)y2;
    ph[tid] = h0;     pl[tid]     = (__bf16)(y0 - (float)h0);
    ph[tid+256] = h1; pl[tid+256] = (__bf16)(y1 - (float)h1);
    ph[tid+512] = h2; pl[tid+512] = (__bf16)(y2 - (float)h2);
}

// =====================================================================
// Final LayerNorm (eps 1e-5, affine) -> hi/lo bf16 planes
// =====================================================================
__global__ __launch_bounds__(256)
void layernorm_kernel(const float* __restrict__ X, const float* __restrict__ w,
                      const float* __restrict__ b, __bf16* __restrict__ Yh,
                      __bf16* __restrict__ Yl)
{
    int row = blockIdx.x, tid = threadIdx.x;
    const float* xr = X + (size_t)row*DHC;
    float v0 = xr[tid], v1 = xr[tid+256], v2 = xr[tid+512];
    __shared__ float rs[256], rs2[256];
    rs[tid]  = v0+v1+v2;
    rs2[tid] = v0*v0+v1*v1+v2*v2;
    __syncthreads();
    for (int s = 128; s; s >>= 1) { if (tid < s) { rs[tid]+=rs[tid+s]; rs2[tid]+=rs2[tid+s]; } __syncthreads(); }
    float mu  = rs[0]/768.0f;
    float var = rs2[0]/768.0f - mu*mu;
    float r = 1.0f/sqrtf(var + 1e-5f);
    float y0 = (v0-mu)*r*w[tid]     + b[tid];
    float y1 = (v1-mu)*r*w[tid+256] + b[tid+256];
    float y2 = (v2-mu)*r*w[tid+512] + b[tid+512];
    __bf16* ph = Yh + (size_t)row*DHC;
    __bf16* pl = Yl + (size_t)row*DHC;
    __bf16 h0 = (__bf16)y0, h1 = (__bf16)y1, h2 = (__bf16)y2;
    ph[tid] = h0;     pl[tid]     = (__bf16)(y0 - (float)h0);
    ph[tid+256] = h1; pl[tid+256] = (__bf16)(y1 - (float)h1);
    ph[tid+512] = h2; pl[tid+512] = (__bf16)(y2 - (float)h2);
}

// =====================================================================
// depthwise causal conv (K=4) + SiLU; src ld ldp, dst ld ldd
// =====================================================================
__global__ __launch_bounds__(64)
void convsilu_kernel(const float* __restrict__ P, int ldp, const float* __restrict__ cw,
                     float* __restrict__ Y, int ldd, int C)
{
    int c = blockIdx.x*64 + threadIdx.x;
    if (c >= C) return;
    int r = blockIdx.y;
    int t = r & (SEQL-1);
    float acc = P[(size_t)r*ldp + c] * cw[c*4+3];
    if (t >= 1) acc += P[(size_t)(r-1)*ldp + c] * cw[c*4+2];
    if (t >= 2) acc += P[(size_t)(r-2)*ldp + c] * cw[c*4+1];
    if (t >= 3) acc += P[(size_t)(r-3)*ldp + c] * cw[c*4+0];
    Y[(size_t)r*ldd + c] = siluf_(acc);
}

// =====================================================================
// per-head L2 norm over DK=48 in place (* scale); base X + row*ld + col0
// =====================================================================
__global__ __launch_bounds__(128)
void l2norm_kernel(float* __restrict__ X, int ld, int col0, float scale)
{
    int row = blockIdx.x;
    int wave = threadIdx.x >> 6, lane = threadIdx.x & 63;
    #pragma unroll
    for (int i = 0; i < 6; ++i) {
        int h = wave*6 + i;
        size_t base = (size_t)row*ld + col0 + h*DKC;
        float v = (lane < DKC) ? X[base + lane] : 0.f;
        float ss = v*v;
        for (int off = 32; off; off >>= 1) ss += __shfl_down(ss, off);
        ss = __shfl(ss, 0);
        float r = scale / sqrtf(ss + 1e-6f);
        if (lane < DKC) X[base + lane] = v*r;
    }
}

// =====================================================================
// beta / decay projections (reads x = hi+lo bf16 planes)
// =====================================================================
__global__ __launch_bounds__(256)
void betag_kernel(const __bf16* __restrict__ XNh, const __bf16* __restrict__ XNl,
                  const float* __restrict__ wb, const float* __restrict__ wa,
                  const float* __restrict__ Alog, const float* __restrict__ dtb,
                  float* __restrict__ Beta, float* __restrict__ Dec)
{
    int row = blockIdx.x, tid = threadIdx.x;
    __shared__ float sx[DHC];
    for (int i = tid; i < DHC; i += 256)
        sx[i] = (float)XNh[(size_t)row*DHC + i] + (float)XNl[(size_t)row*DHC + i];
    __syncthreads();
    int wave = tid >> 6, lane = tid & 63;
    for (int d = 0; d < 6; ++d) {
        int out = wave*6 + d;
        const float* wr = (out < NHC) ? (wb + out*DHC) : (wa + (out-NHC)*DHC);
        float acc = 0.f;
        for (int j = lane; j < DHC; j += 64) acc += sx[j]*wr[j];
        for (int off = 32; off; off >>= 1) acc += __shfl_down(acc, off);
        if (lane == 0) {
            if (out < NHC) {
                Beta[(size_t)row*NHC + out] = sigmoidf_(acc);
            } else {
                int h = out - NHC;
                float sp = acc + dtb[h];
                sp = (sp > 20.f) ? sp : log1pf(expf(sp));
                Dec[(size_t)row*NHC + h] = expf(-expf(Alog[h]) * sp);
            }
        }
    }
}

// =====================================================================
// gated delta-rule scan, software-pipelined:
// double-buffered LDS token slot (194 floats: k|q|v|dec|beta), depth-2
// register prefetch (issue-early / write-late), ONE barrier per token.
// q/k/v packed in QKV[row][2304] (q|k|v).
// =====================================================================
#define SCAN_STEP(CUR, T)                                                   \
    {                                                                       \
        float dec = sbuf[CUR][192], beta = sbuf[CUR][193];                  \
        const float* sk = &sbuf[CUR][0];                                    \
        const float* sq = &sbuf[CUR][48];                                   \
        const float* sv = &sbuf[CUR][96];                                   \
        float pv0 = 0.f, pv1 = 0.f;                                         \
        _Pragma("unroll")                                                   \
        for (int i = 0; i < 12; i += 2) {                                   \
            S[i]   *= dec; pv0 += sk[rg*12+i]  *S[i];                       \
            S[i+1] *= dec; pv1 += sk[rg*12+i+1]*S[i+1];                     \
        }                                                                   \
        float pv = pv0 + pv1;                                               \
        pv += __shfl_xor(pv, 1); pv += __shfl_xor(pv, 2);                   \
        float dvv = beta * (sv[vc] - pv);                                   \
        float po0 = 0.f, po1 = 0.f;                                         \
        _Pragma("unroll")                                                   \
        for (int i = 0; i < 12; i += 2) {                                   \
            S[i]   += sk[rg*12+i]  *dvv; po0 += sq[rg*12+i]  *S[i];         \
            S[i+1] += sk[rg*12+i+1]*dvv; po1 += sq[rg*12+i+1]*S[i+1];       \
        }                                                                   \
        float po = po0 + po1;                                               \
        po += __shfl_xor(po, 1); po += __shfl_xor(po, 2);                   \
        if (rg == 0) op[(size_t)(T)*VDC + vc] = po;                         \
    }

__global__ __launch_bounds__(384)
void scan_kernel(const float* __restrict__ QKV, const float* __restrict__ Beta,
                 const float* __restrict__ Dec, float* __restrict__ O)
{
    int bid = blockIdx.x;
    int seq = bid / NHC, h = bid % NHC;
    int tid = threadIdx.x;
    int vc = tid >> 2, rg = tid & 3;
    __shared__ float sbuf[2][194];

    float S[12];
    #pragma unroll
    for (int i = 0; i < 12; ++i) S[i] = 0.f;

    float* op = O + (size_t)seq*SEQL*VDC + h*DVC;

    // loader assignment: elem e<48 -> k, e<96 -> q, e<192 -> v, 192 dec, 193 beta
    const float* gptr = QKV;     // dummy init, overwritten for loaders
    int gstride = 0;
    const bool ldr = (tid < 194);
    if (tid < 192) {
        int col;
        if (tid < 48)       col = 576  + h*DKC + tid;        // k
        else if (tid < 96)  col =        h*DKC + (tid - 48); // q
        else                col = 1152 + h*DVC + (tid - 96); // v
        gptr = QKV + (size_t)seq*SEQL*2304 + col;
        gstride = 2304;
    } else if (tid == 192) {
        gptr = Dec  + (size_t)seq*SEQL*NHC + h;  gstride = NHC;
    } else if (tid == 193) {
        gptr = Beta + (size_t)seq*SEQL*NHC + h;  gstride = NHC;
    }

    // prologue: LDS[0] = token 0; pA = token 1
    float pA = 0.f, pB = 0.f;
    if (ldr) {
        sbuf[0][tid] = gptr[0];
        pA = gptr[gstride];
    }
    __syncthreads();

    int cur = 0;
    for (int t = 0; t < SEQL; t += 2) {
        // body 1: issue load t+2 early; compute token t; write token t+1 late
        {
            int tn = t + 2; if (tn > SEQL-1) tn = SEQL-1;
            if (ldr) pB = gptr[(size_t)tn * gstride];
            SCAN_STEP(cur, t)
            if (ldr) sbuf[cur^1][tid] = pA;
            __syncthreads();
            cur ^= 1;
        }
        // body 2: issue load t+3 early; compute token t+1; write token t+2 late
        {
            int tn = t + 3; if (tn > SEQL-1) tn = SEQL-1;
            if (ldr) pA = gptr[(size_t)tn * gstride];
            SCAN_STEP(cur, t+1)
            if (ldr) sbuf[cur^1][tid] = pB;
            __syncthreads();
            cur ^= 1;
        }
    }
}

// =====================================================================
// o post: rms(O)*onorm * gate*sigmoid(gate) -> hi/lo bf16
// =====================================================================
__global__ __launch_bounds__(128)
void opost_kernel(const float* __restrict__ O, const float* __restrict__ G, int ldg,
                  const float* __restrict__ onorm, __bf16* __restrict__ Oh,
                  __bf16* __restrict__ Ol)
{
    int row = blockIdx.x;
    int wave = threadIdx.x >> 6, lane = threadIdx.x & 63;
    #pragma unroll
    for (int i = 0; i < 6; ++i) {
        int h = wave*6 + i;
        size_t baseO = (size_t)row*VDC + h*DVC;
        size_t baseG = (size_t)row*ldg + h*DVC;
        float a = O[baseO + lane];
        float c = (lane < 32) ? O[baseO + 64 + lane] : 0.f;
        float ss = a*a + c*c;
        for (int off = 32; off; off >>= 1) ss += __shfl_down(ss, off);
        ss = __shfl(ss, 0);
        float r = 1.0f/sqrtf(ss/96.0f + 1e-6f);
        float ga = G[baseG + lane];
        float v0 = a*r*onorm[lane]*ga*sigmoidf_(ga);
        { __bf16 hh = (__bf16)v0; Oh[baseO+lane] = hh; Ol[baseO+lane] = (__bf16)(v0 - (float)hh); }
        if (lane < 32) {
            float gb = G[baseG + 64 + lane];
            float v1 = c*r*onorm[64+lane]*gb*sigmoidf_(gb);
            __bf16 hh = (__bf16)v1; Oh[baseO+64+lane] = hh; Ol[baseO+64+lane] = (__bf16)(v1 - (float)hh);
        }
    }
}

// =====================================================================
static inline void gemm3(const __bf16* Ah, const __bf16* Al, const __bf16* Wh, const __bf16* Wl,
                         int K, int ldc, int mode, float* Cf, const float* bias,
                         const float* bias2, const float* res, __bf16* Ch, __bf16* Cl,
                         const float* aux, hipStream_t s)
{
    dim3 grid(ldc/128, RTOT/128);
    hipLaunchKernelGGL(gemm3_kernel, grid, dim3(256), 0, s, Ah, Al, Wh, Wl, K, ldc, mode,
                       Cf, bias, bias2, res, Ch, Cl, aux);
}

extern "C" void kernel_launch(void* const* d_in, const int* in_sizes, int n_in,
                              void* d_out, int out_size, void* d_ws, size_t ws_size,
                              hipStream_t stream)
{
    const float* z       = (const float*)d_in[0];
    const float* actions = (const float*)d_in[1];
    const float* enc_w   = (const float*)d_in[2];
    const float* enc_b   = (const float*)d_in[3];
    const float* ap_w    = (const float*)d_in[4];
    const float* ap_b    = (const float*)d_in[5];
    const float* temb    = (const float*)d_in[6];
    const float* ln_w    = (const float*)d_in[7];
    const float* ln_b    = (const float*)d_in[8];
    const float* dec_w   = (const float*)d_in[9];
    const float* dec_b   = (const float*)d_in[10];
    const float* n1      = (const float*)d_in[11];
    const float* n2      = (const float*)d_in[12];
    const float* wq      = (const float*)d_in[13];
    const float* cq      = (const float*)d_in[14];
    const float* wk      = (const float*)d_in[15];
    const float* ck      = (const float*)d_in[16];
    const float* wv      = (const float*)d_in[17];
    const float* cv      = (const float*)d_in[18];
    const float* wb      = (const float*)d_in[19];
    const float* wa      = (const float*)d_in[20];
    const float* A_log   = (const float*)d_in[21];
    const float* dt_bias = (const float*)d_in[22];
    const float* wg      = (const float*)d_in[23];
    const float* onorm   = (const float*)d_in[24];
    const float* wo      = (const float*)d_in[25];
    const float* w1      = (const float*)d_in[26];
    const float* w2      = (const float*)d_in[27];
    const float* w3      = (const float*)d_in[28];

    const size_t R = RTOT;
    const float qscale = 0.14433756729740643f;   // 48^-0.5

    // ---- workspace layout (235.2 MB total; proven ws_size >= 239.96 MB) ----
    float* X    = (float*)d_ws;                  // 768R fp32: residual stream
    float* BUF1 = X    + 768*R;                  // 1152R fp32: qk-pre / v-pre / GATE; A1h alias
    float* O    = BUF1 + 1152*R;                 // 1152R fp32: scan out; A1l alias
    float* QKV  = O    + 1152*R;                 // 2304R fp32: conv out (q|k|v, ld2304); zh/zl, Oh/Ol, A1f alias
    float* BETA = QKV  + 2304*R;                 // 12R
    float* DEC  = BETA + 12*R;                   // 12R
    float* TMP  = DEC  + 12*R;                   // 32*768
    __bf16* XNh = (__bf16*)(TMP + 32*768);       // 768R
    __bf16* XNl = XNh + 768*R;                   // 768R
    __bf16* WS0 = XNl + 768*R;                   // 16,515,072 bf16 weight scratch

    const size_t need = (size_t)(768+1152+1152+2304+24)*R*4 + 32*768*4
                      + ((size_t)1536*R + 16515072)*2;
    if (ws_size < need) return;

    // aliases
    __bf16* zh  = (__bf16*)QKV;                  // 1024R
    __bf16* zl  = zh + 1024*R;
    __bf16* Oh  = (__bf16*)QKV;                  // 1152R
    __bf16* Ol  = Oh + 1152*R;
    float*  A1f = QKV;                           // 2048R fp32 (ldc 2048)
    __bf16* A1h = (__bf16*)BUF1;                 // 2048R bf16
    __bf16* A1l = (__bf16*)O;                    // 2048R bf16

    // ---- encoder ----
    {
        __bf16* ench = WS0;                       __bf16* encl = ench + (size_t)768*1024;
        __bf16* aph  = encl + (size_t)768*1024;   __bf16* apl  = aph  + (size_t)768*768;

        CvtBatch8 eb{};
        eb.src[0]=z;     eb.dh[0]=zh;   eb.dl[0]=zl;   eb.ldv[0]=1024; eb.cols[0]=1024; eb.rowend[0]=8192;
        eb.src[1]=enc_w; eb.dh[1]=ench; eb.dl[1]=encl; eb.ldv[1]=1024; eb.cols[1]=1024; eb.rowend[1]=8960;
        eb.src[2]=ap_w;  eb.dh[2]=aph;  eb.dl[2]=apl;  eb.ldv[2]=770;  eb.cols[2]=768;  eb.rowend[2]=9728;
        hipLaunchKernelGGL(cvt_batch_kernel, dim3(9728), dim3(256), 0, stream, eb, 3);

        hipLaunchKernelGGL(bias2_kernel, dim3(32), dim3(256), 0, stream, actions, ap_w, ap_b, temb, TMP);
        gemm3(zh, zl, ench, encl, 1024, 768, 1, nullptr, enc_b, nullptr, nullptr, XNh, XNl, nullptr, stream);
        gemm3(XNh, XNl, aph, apl, 768, 768, 0, X, nullptr, TMP, nullptr, nullptr, nullptr, nullptr, stream);
    }

    // ---- layers ----
    for (int l = 0; l < NLAY; ++l) {
        // per-layer weight planes in shared scratch (stream-ordered reuse)
        __bf16* qkh = WS0;                        __bf16* qkl = qkh + (size_t)1152*768;
        __bf16* vh  = qkl + (size_t)1152*768;     __bf16* vl  = vh  + (size_t)1152*768;
        __bf16* gh  = vl  + (size_t)1152*768;     __bf16* gl_ = gh  + (size_t)1152*768;
        __bf16* woh = gl_ + (size_t)1152*768;     __bf16* wol = woh + (size_t)768*1152;
        __bf16* w1h = wol + (size_t)768*1152;     __bf16* w1l = w1h + (size_t)2048*768;
        __bf16* w3h = w1l + (size_t)2048*768;     __bf16* w3l = w3h + (size_t)2048*768;
        __bf16* w2h = w3l + (size_t)2048*768;     __bf16* w2l = w2h + (size_t)768*2048;

        // one fused conversion launch for all 8 weight tensors of this layer
        CvtBatch8 lb{};
        lb.src[0]=wq + (size_t)l*KDC*DHC; lb.dh[0]=qkh;                   lb.dl[0]=qkl;                   lb.ldv[0]=768;  lb.cols[0]=768;  lb.rowend[0]=576;
        lb.src[1]=wk + (size_t)l*KDC*DHC; lb.dh[1]=qkh+(size_t)576*768;   lb.dl[1]=qkl+(size_t)576*768;   lb.ldv[1]=768;  lb.cols[1]=768;  lb.rowend[1]=1152;
        lb.src[2]=wv + (size_t)l*VDC*DHC; lb.dh[2]=vh;                    lb.dl[2]=vl;                    lb.ldv[2]=768;  lb.cols[2]=768;  lb.rowend[2]=2304;
        lb.src[3]=wg + (size_t)l*VDC*DHC; lb.dh[3]=gh;                    lb.dl[3]=gl_;                   lb.ldv[3]=768;  lb.cols[3]=768;  lb.rowend[3]=3456;
        lb.src[4]=wo + (size_t)l*DHC*VDC; lb.dh[4]=woh;                   lb.dl[4]=wol;                   lb.ldv[4]=1152; lb.cols[4]=1152; lb.rowend[4]=4224;
        lb.src[5]=w1 + (size_t)l*IMC*DHC; lb.dh[5]=w1h;                   lb.dl[5]=w1l;                   lb.ldv[5]=768;  lb.cols[5]=768;  lb.rowend[5]=6272;
        lb.src[6]=w3 + (size_t)l*IMC*DHC; lb.dh[6]=w3h;                   lb.dl[6]=w3l;                   lb.ldv[6]=768;  lb.cols[6]=768;  lb.rowend[6]=8320;
        lb.src[7]=w2 + (size_t)l*DHC*IMC; lb.dh[7]=w2h;                   lb.dl[7]=w2l;                   lb.ldv[7]=2048; lb.cols[7]=2048; lb.rowend[7]=9088;
        hipLaunchKernelGGL(cvt_batch_kernel, dim3(9088), dim3(256), 0, stream, lb, 8);

        // attn input norm -> hi/lo planes
        hipLaunchKernelGGL(rmsnorm_kernel, dim3(RTOT), dim3(256), 0, stream, X, n1 + l*DHC, XNh, XNl);

        // qk projection -> BUF1, conv q,k -> QKV[:,0:1152]
        gemm3(XNh, XNl, qkh, qkl, 768, 1152, 0, BUF1, nullptr, nullptr, nullptr, nullptr, nullptr, nullptr, stream);
        hipLaunchKernelGGL(convsilu_kernel, dim3(9,  RTOT), dim3(64), 0, stream, BUF1,       1152, cq + (size_t)l*KDC*4, QKV,        2304, KDC);
        hipLaunchKernelGGL(convsilu_kernel, dim3(9,  RTOT), dim3(64), 0, stream, BUF1 + 576, 1152, ck + (size_t)l*KDC*4, QKV + 576,  2304, KDC);
        // v projection -> BUF1 (overwrite), conv v -> QKV[:,1152:2304]
        gemm3(XNh, XNl, vh, vl, 768, 1152, 0, BUF1, nullptr, nullptr, nullptr, nullptr, nullptr, nullptr, stream);
        hipLaunchKernelGGL(convsilu_kernel, dim3(18, RTOT), dim3(64), 0, stream, BUF1,       1152, cv + (size_t)l*VDC*4, QKV + 1152, 2304, VDC);
        // gate projection -> BUF1 = GATE
        gemm3(XNh, XNl, gh, gl_, 768, 1152, 0, BUF1, nullptr, nullptr, nullptr, nullptr, nullptr, nullptr, stream);
        // beta / decay
        hipLaunchKernelGGL(betag_kernel, dim3(RTOT), dim3(256), 0, stream,
                           XNh, XNl, wb + (size_t)l*NHC*DHC, wa + (size_t)l*NHC*DHC,
                           A_log + l*NHC, dt_bias + l*NHC, BETA, DEC);

        // l2 norm q (scaled), k
        hipLaunchKernelGGL(l2norm_kernel, dim3(RTOT), dim3(128), 0, stream, QKV, 2304, 0,   qscale);
        hipLaunchKernelGGL(l2norm_kernel, dim3(RTOT), dim3(128), 0, stream, QKV, 2304, 576, 1.0f);

        // recurrent delta-rule scan (pipelined)
        hipLaunchKernelGGL(scan_kernel, dim3(32*NHC), dim3(384), 0, stream, QKV, BETA, DEC, O);

        // opost -> Oh/Ol (QKV region; q/k/v dead after scan)
        hipLaunchKernelGGL(opost_kernel, dim3(RTOT), dim3(128), 0, stream, O, BUF1, 1152,
                           onorm + l*DVC, Oh, Ol);
        gemm3(Oh, Ol, woh, wol, 1152, 768, 0, X, nullptr, nullptr, X, nullptr, nullptr, nullptr, stream);

        // MLP
        hipLaunchKernelGGL(rmsnorm_kernel, dim3(RTOT), dim3(256), 0, stream, X, n2 + l*DHC, XNh, XNl);
        gemm3(XNh, XNl, w1h, w1l, 768, 2048, 0, A1f, nullptr, nullptr, nullptr, nullptr, nullptr, nullptr, stream);
        gemm3(XNh, XNl, w3h, w3l, 768, 2048, 2, nullptr, nullptr, nullptr, nullptr, A1h, A1l, A1f, stream);
        gemm3(A1h, A1l, w2h, w2l, 2048, 768, 0, X, nullptr, nullptr, X, nullptr, nullptr, nullptr, stream);
    }

    // ---- final LN + decoder + residual ----
    {
        __bf16* dech = WS0;  __bf16* decl = dech + (size_t)1024*768;
        CvtBatch8 db{};
        db.src[0]=dec_w; db.dh[0]=dech; db.dl[0]=decl; db.ldv[0]=768; db.cols[0]=768; db.rowend[0]=1024;
        hipLaunchKernelGGL(cvt_batch_kernel, dim3(1024), dim3(256), 0, stream, db, 1);
        hipLaunchKernelGGL(layernorm_kernel, dim3(RTOT), dim3(256), 0, stream, X, ln_w, ln_b, XNh, XNl);
        gemm3(XNh, XNl, dech, decl, 768, 1024, 0, (float*)d_out, dec_b, nullptr, z, nullptr, nullptr, nullptr, stream);
    }
}

// Round 10
// 5795.571 us; speedup vs baseline: 2.2471x; 1.0153x over previous
//
#include <hip/hip_runtime.h>
#include <math.h>

// ---- problem constants ----
#define RTOT 8192   // B*T*N token rows
#define SEQL 256    // tokens per folded sequence
#define DHC 768
#define KDC 576
#define VDC 1152
#define IMC 2048
#define NHC 12
#define DKC 48
#define DVC 96
#define NLAY 5

typedef float f4 __attribute__((ext_vector_type(4)));
typedef __bf16 v8bf __attribute__((ext_vector_type(8)));

__device__ __forceinline__ float sigmoidf_(float x){ return 1.0f/(1.0f+expf(-x)); }
__device__ __forceinline__ float siluf_(float x){ return x/(1.0f+expf(-x)); }

__device__ __forceinline__ void gl16(const void* g, void* l) {
    __builtin_amdgcn_global_load_lds((const __attribute__((address_space(1))) void*)g,
                                     (__attribute__((address_space(3))) void*)l, 16, 0, 0);
}
#define MFMA_BF16(a,b,c) __builtin_amdgcn_mfma_f32_16x16x32_bf16((a),(b),(c),0,0,0)

// =====================================================================
// bf16x3 / bf16x2 MFMA GEMM: C[M=8192, N=ldc] = A[M,K] @ W[N,K]^T.
// HASAL=true : acc += Al*Bh + Ah*Bl + Ah*Bh  (bf16x3, ~fp32)
// HASAL=false: acc += Ah*Bl + Ah*Bh          (bf16x2, ~2^-9 rel err)
// BM=BN=128, BK=32, 256 threads = 4 waves, each wave 64x64 (4x4 frags).
// =====================================================================
template<bool HASAL>
__global__ __launch_bounds__(256)
void gemm3_kernel(const __bf16* __restrict__ Ah, const __bf16* __restrict__ Al,
                  const __bf16* __restrict__ Wh, const __bf16* __restrict__ Wl,
                  int K, int ldc, int mode,
                  float* Cf, const float* bias, const float* bias2, const float* res,
                  __bf16* Ch, __bf16* Cl, const float* aux)
{
    __shared__ __bf16 sAh[128*32], sBh[128*32], sBl[128*32];
    __shared__ __bf16 sAl[HASAL ? 128*32 : 16];
    const int tid  = threadIdx.x;
    const int m0   = blockIdx.y * 128, n0 = blockIdx.x * 128;
    const int lane = tid & 63, wv = tid >> 6;
    const int wm   = (wv & 1) * 64, wn = (wv >> 1) * 64;

    // LDS dest linear (global_load_lds rule); swizzle in global source k-offset
    // and read addresses (rule #21 both-sides).
    const int o0 = tid * 16, o1 = o0 + 4096;
    const int r0 = o0 >> 6, s0 = (o0 >> 4) & 3;
    const int r1 = o1 >> 6, s1 = (o1 >> 4) & 3;
    const int k0 = (s0 ^ ((r0 >> 1) & 3)) * 8;
    const int k1 = (s1 ^ ((r1 >> 1) & 3)) * 8;

    const __bf16* gA0h = Ah + (size_t)(m0 + r0) * K + k0;
    const __bf16* gA1h = Ah + (size_t)(m0 + r1) * K + k1;
    const __bf16* gA0l = HASAL ? (Al + (size_t)(m0 + r0) * K + k0) : nullptr;
    const __bf16* gA1l = HASAL ? (Al + (size_t)(m0 + r1) * K + k1) : nullptr;
    const __bf16* gB0h = Wh + (size_t)(n0 + r0) * K + k0;
    const __bf16* gB1h = Wh + (size_t)(n0 + r1) * K + k1;
    const __bf16* gB0l = Wl + (size_t)(n0 + r0) * K + k0;
    const __bf16* gB1l = Wl + (size_t)(n0 + r1) * K + k1;

    const int fr = lane & 15, g8 = lane >> 4;
    int aoff[4], boff[4];
    #pragma unroll
    for (int f = 0; f < 4; ++f) {
        int ra = wm + f*16 + fr;
        aoff[f] = ra*32 + (g8 ^ ((ra >> 1) & 3)) * 8;
        int rb = wn + f*16 + fr;
        boff[f] = rb*32 + (g8 ^ ((rb >> 1) & 3)) * 8;
    }

    f4 acc[4][4];
    const f4 zero4 = {0.f, 0.f, 0.f, 0.f};
    #pragma unroll
    for (int i = 0; i < 4; ++i)
        #pragma unroll
        for (int j = 0; j < 4; ++j) acc[i][j] = zero4;

    for (int kt = 0; kt < K; kt += 32) {
        gl16(gA0h + kt, (char*)sAh + o0);
        gl16(gA1h + kt, (char*)sAh + o1);
        if constexpr (HASAL) {
            gl16(gA0l + kt, (char*)sAl + o0);
            gl16(gA1l + kt, (char*)sAl + o1);
        }
        gl16(gB0h + kt, (char*)sBh + o0);
        gl16(gB1h + kt, (char*)sBh + o1);
        gl16(gB0l + kt, (char*)sBl + o0);
        gl16(gB1l + kt, (char*)sBl + o1);
        __syncthreads();

        v8bf bhv[4], blv[4];
        #pragma unroll
        for (int f = 0; f < 4; ++f) {
            bhv[f] = *(const v8bf*)(sBh + boff[f]);
            blv[f] = *(const v8bf*)(sBl + boff[f]);
        }
        #pragma unroll
        for (int i = 0; i < 4; ++i) {
            v8bf ahv = *(const v8bf*)(sAh + aoff[i]);
            v8bf alv;
            if constexpr (HASAL) alv = *(const v8bf*)(sAl + aoff[i]);
            #pragma unroll
            for (int j = 0; j < 4; ++j) {
                f4 t = acc[i][j];
                if constexpr (HASAL) t = MFMA_BF16(alv, bhv[j], t);   // Alo*Bhi
                t = MFMA_BF16(ahv, blv[j], t);                        // Ahi*Blo
                acc[i][j] = MFMA_BF16(ahv, bhv[j], t);                // Ahi*Bhi
            }
        }
        __syncthreads();
    }

    // epilogue: D[row=(lane>>4)*4+j][col=lane&15] per frag
    const int rb4 = (lane >> 4) * 4;
    #pragma unroll
    for (int i = 0; i < 4; ++i) {
        #pragma unroll
        for (int jf = 0; jf < 4; ++jf) {
            int col = n0 + wn + jf*16 + fr;
            #pragma unroll
            for (int j = 0; j < 4; ++j) {
                int row = m0 + wm + i*16 + rb4 + j;
                size_t idx = (size_t)row * ldc + col;
                float v = acc[i][jf][j];
                if (bias)  v += bias[col];
                if (bias2) v += bias2[(size_t)(row >> 8) * ldc + col];
                if (res)   v += res[idx];
                if (mode == 2) v = siluf_(aux[idx]) * v;
                if (mode == 0) {
                    Cf[idx] = v;
                } else {
                    __bf16 h = (__bf16)v;
                    Ch[idx] = h;
                    if (Cl) Cl[idx] = (__bf16)(v - (float)h);
                }
            }
        }
    }
}

// =====================================================================
// batched fp32 -> (hi,lo) bf16 conversion: up to 8 jobs in one launch
// =====================================================================
struct CvtBatch8 {
    const float* src[8];
    __bf16* dh[8];
    __bf16* dl[8];
    int ldv[8];
    int cols[8];
    int rowend[8];
};

__global__ __launch_bounds__(256)
void cvt_batch_kernel(CvtBatch8 b, int njobs)
{
    int r = blockIdx.x;
    int j = 0;
    while (j < njobs - 1 && r >= b.rowend[j]) ++j;
    int row0 = (j == 0) ? 0 : b.rowend[j-1];
    int lr = r - row0;
    const float* s = b.src[j] + (size_t)lr * b.ldv[j];
    __bf16* ph = b.dh[j] + (size_t)lr * b.cols[j];
    __bf16* pl = b.dl[j] + (size_t)lr * b.cols[j];
    int cols = b.cols[j];
    for (int c = threadIdx.x; c < cols; c += 256) {
        float v = s[c];
        __bf16 hh = (__bf16)v;
        ph[c] = hh;
        pl[c] = (__bf16)(v - (float)hh);
    }
}

// =====================================================================
__global__ __launch_bounds__(256)
void bias2_kernel(const float* __restrict__ actions, const float* __restrict__ ap_w,
                  const float* __restrict__ ap_b, const float* __restrict__ temb,
                  float* __restrict__ B2)
{
    int bt = blockIdx.x;
    int t  = bt & 7;
    float a0 = actions[bt*2], a1 = actions[bt*2+1];
    for (int c = threadIdx.x; c < DHC; c += 256)
        B2[bt*DHC + c] = ap_b[c] + temb[t*DHC + c] + a0*ap_w[c*770 + 768] + a1*ap_w[c*770 + 769];
}

// =====================================================================
__global__ __launch_bounds__(256)
void rmsnorm_kernel(const float* __restrict__ X, const float* __restrict__ w,
                    __bf16* __restrict__ Yh, __bf16* __restrict__ Yl)
{
    int row = blockIdx.x, tid = threadIdx.x;
    const float* xr = X + (size_t)row*DHC;
    float v0 = xr[tid], v1 = xr[tid+256], v2 = xr[tid+512];
    __shared__ float red[256];
    red[tid] = v0*v0 + v1*v1 + v2*v2;
    __syncthreads();
    for (int s = 128; s; s >>= 1) { if (tid < s) red[tid] += red[tid+s]; __syncthreads(); }
    float r = 1.0f/sqrtf(red[0]/768.0f + 1e-6f);
    float y0 = v0*r*w[tid], y1 = v1*r*w[tid+256], y2 = v2*r*w[tid+512];
    __bf16* ph = Yh + (size_t)row*DHC;
    __bf16* pl = Yl + (size_t)row*DHC;
    __bf16 h0 = (__bf16)y0, h1 = (__bf16)y1, h2 = (__bf16)y2;
    ph[tid] = h0;     pl[tid]     = (__bf16)(y0 - (float)h0);
    ph[tid+256] = h1; pl[tid+256] = (__bf16)(y1 - (float)h1);
    ph[tid+512] = h2; pl[tid+512] = (__bf16)(y2 - (float)h2);
}

// =====================================================================
__global__ __launch_bounds__(256)
void layernorm_kernel(const float* __restrict__ X, const float* __restrict__ w,
                      const float* __restrict__ b, __bf16* __restrict__ Yh,
                      __bf16* __restrict__ Yl)
{
    int row = blockIdx.x, tid = threadIdx.x;
    const float* xr = X + (size_t)row*DHC;
    float v0 = xr[tid], v1 = xr[tid+256], v2 = xr[tid+512];
    __shared__ float rs[256], rs2[256];
    rs[tid]  = v0+v1+v2;
    rs2[tid] = v0*v0+v1*v1+v2*v2;
    __syncthreads();
    for (int s = 128; s; s >>= 1) { if (tid < s) { rs[tid]+=rs[tid+s]; rs2[tid]+=rs2[tid+s]; } __syncthreads(); }
    float mu  = rs[0]/768.0f;
    float var = rs2[0]/768.0f - mu*mu;
    float r = 1.0f/sqrtf(var + 1e-5f);
    float y0 = (v0-mu)*r*w[tid]     + b[tid];
    float y1 = (v1-mu)*r*w[tid+256] + b[tid+256];
    float y2 = (v2-mu)*r*w[tid+512] + b[tid+512];
    __bf16* ph = Yh + (size_t)row*DHC;
    __bf16* pl = Yl + (size_t)row*DHC;
    __bf16 h0 = (__bf16)y0, h1 = (__bf16)y1, h2 = (__bf16)y2;
    ph[tid] = h0;     pl[tid]     = (__bf16)(y0 - (float)h0);
    ph[tid+256] = h1; pl[tid+256] = (__bf16)(y1 - (float)h1);
    ph[tid+512] = h2; pl[tid+512] = (__bf16)(y2 - (float)h2);
}

// =====================================================================
__global__ __launch_bounds__(64)
void convsilu_kernel(const float* __restrict__ P, int ldp, const float* __restrict__ cw,
                     float* __restrict__ Y, int ldd, int C)
{
    int c = blockIdx.x*64 + threadIdx.x;
    if (c >= C) return;
    int r = blockIdx.y;
    int t = r & (SEQL-1);
    float acc = P[(size_t)r*ldp + c] * cw[c*4+3];
    if (t >= 1) acc += P[(size_t)(r-1)*ldp + c] * cw[c*4+2];
    if (t >= 2) acc += P[(size_t)(r-2)*ldp + c] * cw[c*4+1];
    if (t >= 3) acc += P[(size_t)(r-3)*ldp + c] * cw[c*4+0];
    Y[(size_t)r*ldd + c] = siluf_(acc);
}

// =====================================================================
__global__ __launch_bounds__(128)
void l2norm_kernel(float* __restrict__ X, int ld, int col0, float scale)
{
    int row = blockIdx.x;
    int wave = threadIdx.x >> 6, lane = threadIdx.x & 63;
    #pragma unroll
    for (int i = 0; i < 6; ++i) {
        int h = wave*6 + i;
        size_t base = (size_t)row*ld + col0 + h*DKC;
        float v = (lane < DKC) ? X[base + lane] : 0.f;
        float ss = v*v;
        for (int off = 32; off; off >>= 1) ss += __shfl_down(ss, off);
        ss = __shfl(ss, 0);
        float r = scale / sqrtf(ss + 1e-6f);
        if (lane < DKC) X[base + lane] = v*r;
    }
}

// =====================================================================
__global__ __launch_bounds__(256)
void betag_kernel(const __bf16* __restrict__ XNh, const __bf16* __restrict__ XNl,
                  const float* __restrict__ wb, const float* __restrict__ wa,
                  const float* __restrict__ Alog, const float* __restrict__ dtb,
                  float* __restrict__ Beta, float* __restrict__ Dec)
{
    int row = blockIdx.x, tid = threadIdx.x;
    __shared__ float sx[DHC];
    for (int i = tid; i < DHC; i += 256)
        sx[i] = (float)XNh[(size_t)row*DHC + i] + (float)XNl[(size_t)row*DHC + i];
    __syncthreads();
    int wave = tid >> 6, lane = tid & 63;
    for (int d = 0; d < 6; ++d) {
        int out = wave*6 + d;
        const float* wr = (out < NHC) ? (wb + out*DHC) : (wa + (out-NHC)*DHC);
        float acc = 0.f;
        for (int j = lane; j < DHC; j += 64) acc += sx[j]*wr[j];
        for (int off = 32; off; off >>= 1) acc += __shfl_down(acc, off);
        if (lane == 0) {
            if (out < NHC) {
                Beta[(size_t)row*NHC + out] = sigmoidf_(acc);
            } else {
                int h = out - NHC;
                float sp = acc + dtb[h];
                sp = (sp > 20.f) ? sp : log1pf(expf(sp));
                Dec[(size_t)row*NHC + h] = expf(-expf(Alog[h]) * sp);
            }
        }
    }
}

// =====================================================================
// gated delta-rule scan — ONE WAVE per (seq,head), zero barriers.
// The recurrence is independent per v-column; only the k-reduction crosses
// lanes (4-lane shfl groups). Lane (g=lane>>2, rg=lane&3) owns v-cols
// g*6..g*6+5 and k-rows rg*12..rg*12+11: S[12][6] = 72 regs/lane.
// Token record (194 floats: k|q|v|dec|beta) double-buffered in LDS,
// depth-2 register prefetch (4 slots/lane), identical reduction tree to
// the round-8 version (bit-identical numerics).
// =====================================================================
#define SCAN_STEP_W(CUR, T)                                                  \
    {                                                                        \
        float dec  = sbuf[CUR][192], beta = sbuf[CUR][193];                  \
        const float* sk = &sbuf[CUR][0];                                     \
        const float* sq = &sbuf[CUR][48];                                    \
        const float* sv = &sbuf[CUR][96];                                    \
        float kx[12], qx[12], vx[6], pv[6], po[6];                           \
        _Pragma("unroll")                                                    \
        for (int i = 0; i < 12; ++i) { kx[i] = sk[rg*12+i]; qx[i] = sq[rg*12+i]; } \
        _Pragma("unroll")                                                    \
        for (int j = 0; j < 6; ++j) vx[j] = sv[g*6+j];                       \
        _Pragma("unroll")                                                    \
        for (int j = 0; j < 6; ++j) {                                        \
            float a0 = 0.f, a1 = 0.f;                                        \
            _Pragma("unroll")                                                \
            for (int i = 0; i < 12; i += 2) {                                \
                S[i][j]   *= dec; a0 += kx[i]  *S[i][j];                     \
                S[i+1][j] *= dec; a1 += kx[i+1]*S[i+1][j];                   \
            }                                                                \
            pv[j] = a0 + a1;                                                 \
        }                                                                    \
        _Pragma("unroll")                                                    \
        for (int j = 0; j < 6; ++j) {                                        \
            pv[j] += __shfl_xor(pv[j], 1);                                   \
            pv[j] += __shfl_xor(pv[j], 2);                                   \
        }                                                                    \
        _Pragma("unroll")                                                    \
        for (int j = 0; j < 6; ++j) {                                        \
            float dvv = beta * (vx[j] - pv[j]);                              \
            float a0 = 0.f, a1 = 0.f;                                        \
            _Pragma("unroll")                                                \
            for (int i = 0; i < 12; i += 2) {                                \
                S[i][j]   += kx[i]  *dvv; a0 += qx[i]  *S[i][j];             \
                S[i+1][j] += kx[i+1]*dvv; a1 += qx[i+1]*S[i+1][j];           \
            }                                                                \
            po[j] = a0 + a1;                                                 \
        }                                                                    \
        _Pragma("unroll")                                                    \
        for (int j = 0; j < 6; ++j) {                                        \
            po[j] += __shfl_xor(po[j], 1);                                   \
            po[j] += __shfl_xor(po[j], 2);                                   \
        }                                                                    \
        if (rg == 0) {                                                       \
            _Pragma("unroll")                                                \
            for (int j = 0; j < 6; ++j) op[(size_t)(T)*VDC + g*6 + j] = po[j]; \
        }                                                                    \
    }

__global__ __launch_bounds__(64)
void scan_kernel(const float* __restrict__ QKV, const float* __restrict__ Beta,
                 const float* __restrict__ Dec, float* __restrict__ O)
{
    int bid = blockIdx.x;              // 384 = 32 seq x 12 head, 1 wave each
    int seq = bid / NHC, h = bid % NHC;
    int lane = threadIdx.x;
    int g = lane >> 2, rg = lane & 3;
    __shared__ float sbuf[2][194];

    float S[12][6];
    #pragma unroll
    for (int i = 0; i < 12; ++i)
        #pragma unroll
        for (int j = 0; j < 6; ++j) S[i][j] = 0.f;

    float* op = O + (size_t)seq*SEQL*VDC + h*DVC;

    // 4 prefetch slots per lane: elements lane, lane+64, lane+128, lane+192
    const float* gp[4]; int gs[4]; bool en[4];
    #pragma unroll
    for (int s = 0; s < 4; ++s) {
        int e = lane + s*64;
        en[s] = (e < 194);
        const float* base = QKV;  int stride = 0;
        if (e < 48)        { base = QKV + (size_t)seq*SEQL*2304 + 576 + h*DKC + e;          stride = 2304; }
        else if (e < 96)   { base = QKV + (size_t)seq*SEQL*2304 + h*DKC + (e-48);           stride = 2304; }
        else if (e < 192)  { base = QKV + (size_t)seq*SEQL*2304 + 1152 + h*DVC + (e-96);    stride = 2304; }
        else if (e == 192) { base = Dec  + (size_t)seq*SEQL*NHC + h;                        stride = NHC; }
        else if (e == 193) { base = Beta + (size_t)seq*SEQL*NHC + h;                        stride = NHC; }
        gp[s] = base; gs[s] = stride;
    }

    // prologue: LDS[0] = token 0; pA = token 1
    float pA[4], pB[4];
    #pragma unroll
    for (int s = 0; s < 4; ++s)
        if (en[s]) { sbuf[0][lane + s*64] = gp[s][0]; pA[s] = gp[s][gs[s]]; }
    __syncthreads();   // single wave: compiles to a cheap lgkmcnt drain

    int cur = 0;
    for (int t = 0; t < SEQL; t += 2) {
        {   // compute token t; prefetch t+2; write t+1 into alt buffer
            int tn = t + 2; if (tn > SEQL-1) tn = SEQL-1;
            #pragma unroll
            for (int s = 0; s < 4; ++s) if (en[s]) pB[s] = gp[s][(size_t)tn * gs[s]];
            SCAN_STEP_W(cur, t)
            #pragma unroll
            for (int s = 0; s < 4; ++s) if (en[s]) sbuf[cur^1][lane + s*64] = pA[s];
            __syncthreads();
            cur ^= 1;
        }
        {   // compute token t+1; prefetch t+3; write t+2
            int tn = t + 3; if (tn > SEQL-1) tn = SEQL-1;
            #pragma unroll
            for (int s = 0; s < 4; ++s) if (en[s]) pA[s] = gp[s][(size_t)tn * gs[s]];
            SCAN_STEP_W(cur, t+1)
            #pragma unroll
            for (int s = 0; s < 4; ++s) if (en[s]) sbuf[cur^1][lane + s*64] = pB[s];
            __syncthreads();
            cur ^= 1;
        }
    }
}

// =====================================================================
__global__ __launch_bounds__(128)
void opost_kernel(const float* __restrict__ O, const float* __restrict__ G, int ldg,
                  const float* __restrict__ onorm, __bf16* __restrict__ Oh,
                  __bf16* __restrict__ Ol)
{
    int row = blockIdx.x;
    int wave = threadIdx.x >> 6, lane = threadIdx.x & 63;
    #pragma unroll
    for (int i = 0; i < 6; ++i) {
        int h = wave*6 + i;
        size_t baseO = (size_t)row*VDC + h*DVC;
        size_t baseG = (size_t)row*ldg + h*DVC;
        float a = O[baseO + lane];
        float c = (lane < 32) ? O[baseO + 64 + lane] : 0.f;
        float ss = a*a + c*c;
        for (int off = 32; off; off >>= 1) ss += __shfl_down(ss, off);
        ss = __shfl(ss, 0);
        float r = 1.0f/sqrtf(ss/96.0f + 1e-6f);
        float ga = G[baseG + lane];
        float v0 = a*r*onorm[lane]*ga*sigmoidf_(ga);
        { __bf16 hh = (__bf16)v0; Oh[baseO+lane] = hh; Ol[baseO+lane] = (__bf16)(v0 - (float)hh); }
        if (lane < 32) {
            float gb = G[baseG + 64 + lane];
            float v1 = c*r*onorm[64+lane]*gb*sigmoidf_(gb);
            __bf16 hh = (__bf16)v1; Oh[baseO+64+lane] = hh; Ol[baseO+64+lane] = (__bf16)(v1 - (float)hh);
        }
    }
}

// =====================================================================
static inline void gemm3(bool hasAl,
                         const __bf16* Ah, const __bf16* Al, const __bf16* Wh, const __bf16* Wl,
                         int K, int ldc, int mode, float* Cf, const float* bias,
                         const float* bias2, const float* res, __bf16* Ch, __bf16* Cl,
                         const float* aux, hipStream_t s)
{
    dim3 grid(ldc/128, RTOT/128);
    if (hasAl)
        hipLaunchKernelGGL(gemm3_kernel<true>,  grid, dim3(256), 0, s, Ah, Al, Wh, Wl, K, ldc, mode,
                           Cf, bias, bias2, res, Ch, Cl, aux);
    else
        hipLaunchKernelGGL(gemm3_kernel<false>, grid, dim3(256), 0, s, Ah, Al, Wh, Wl, K, ldc, mode,
                           Cf, bias, bias2, res, Ch, Cl, aux);
}

extern "C" void kernel_launch(void* const* d_in, const int* in_sizes, int n_in,
                              void* d_out, int out_size, void* d_ws, size_t ws_size,
                              hipStream_t stream)
{
    const float* z       = (const float*)d_in[0];
    const float* actions = (const float*)d_in[1];
    const float* enc_w   = (const float*)d_in[2];
    const float* enc_b   = (const float*)d_in[3];
    const float* ap_w    = (const float*)d_in[4];
    const float* ap_b    = (const float*)d_in[5];
    const float* temb    = (const float*)d_in[6];
    const float* ln_w    = (const float*)d_in[7];
    const float* ln_b    = (const float*)d_in[8];
    const float* dec_w   = (const float*)d_in[9];
    const float* dec_b   = (const float*)d_in[10];
    const float* n1      = (const float*)d_in[11];
    const float* n2      = (const float*)d_in[12];
    const float* wq      = (const float*)d_in[13];
    const float* cq      = (const float*)d_in[14];
    const float* wk      = (const float*)d_in[15];
    const float* ck      = (const float*)d_in[16];
    const float* wv      = (const float*)d_in[17];
    const float* cv      = (const float*)d_in[18];
    const float* wb      = (const float*)d_in[19];
    const float* wa      = (const float*)d_in[20];
    const float* A_log   = (const float*)d_in[21];
    const float* dt_bias = (const float*)d_in[22];
    const float* wg      = (const float*)d_in[23];
    const float* onorm   = (const float*)d_in[24];
    const float* wo      = (const float*)d_in[25];
    const float* w1      = (const float*)d_in[26];
    const float* w2      = (const float*)d_in[27];
    const float* w3      = (const float*)d_in[28];

    const size_t R = RTOT;
    const float qscale = 0.14433756729740643f;   // 48^-0.5

    // ---- workspace layout (unchanged from round 8; 235.2 MB) ----
    float* X    = (float*)d_ws;
    float* BUF1 = X    + 768*R;
    float* O    = BUF1 + 1152*R;
    float* QKV  = O    + 1152*R;
    float* BETA = QKV  + 2304*R;
    float* DEC  = BETA + 12*R;
    float* TMP  = DEC  + 12*R;
    __bf16* XNh = (__bf16*)(TMP + 32*768);
    __bf16* XNl = XNh + 768*R;
    __bf16* WS0 = XNl + 768*R;

    const size_t need = (size_t)(768+1152+1152+2304+24)*R*4 + 32*768*4
                      + ((size_t)1536*R + 16515072)*2;
    if (ws_size < need) return;

    // aliases
    __bf16* zh  = (__bf16*)QKV;
    __bf16* zl  = zh + 1024*R;
    __bf16* Oh  = (__bf16*)QKV;
    __bf16* Ol  = Oh + 1152*R;
    float*  A1f = QKV;
    __bf16* A1h = (__bf16*)BUF1;

    // ---- encoder (bf16x3) ----
    {
        __bf16* ench = WS0;                       __bf16* encl = ench + (size_t)768*1024;
        __bf16* aph  = encl + (size_t)768*1024;   __bf16* apl  = aph  + (size_t)768*768;

        CvtBatch8 eb{};
        eb.src[0]=z;     eb.dh[0]=zh;   eb.dl[0]=zl;   eb.ldv[0]=1024; eb.cols[0]=1024; eb.rowend[0]=8192;
        eb.src[1]=enc_w; eb.dh[1]=ench; eb.dl[1]=encl; eb.ldv[1]=1024; eb.cols[1]=1024; eb.rowend[1]=8960;
        eb.src[2]=ap_w;  eb.dh[2]=aph;  eb.dl[2]=apl;  eb.ldv[2]=770;  eb.cols[2]=768;  eb.rowend[2]=9728;
        hipLaunchKernelGGL(cvt_batch_kernel, dim3(9728), dim3(256), 0, stream, eb, 3);

        hipLaunchKernelGGL(bias2_kernel, dim3(32), dim3(256), 0, stream, actions, ap_w, ap_b, temb, TMP);
        gemm3(true, zh, zl, ench, encl, 1024, 768, 1, nullptr, enc_b, nullptr, nullptr, XNh, XNl, nullptr, stream);
        gemm3(true, XNh, XNl, aph, apl, 768, 768, 0, X, nullptr, TMP, nullptr, nullptr, nullptr, nullptr, stream);
    }

    // ---- layers ----
    for (int l = 0; l < NLAY; ++l) {
        __bf16* qkh = WS0;                        __bf16* qkl = qkh + (size_t)1152*768;
        __bf16* vh  = qkl + (size_t)1152*768;     __bf16* vl  = vh  + (size_t)1152*768;
        __bf16* gh  = vl  + (size_t)1152*768;     __bf16* gl_ = gh  + (size_t)1152*768;
        __bf16* woh = gl_ + (size_t)1152*768;     __bf16* wol = woh + (size_t)768*1152;
        __bf16* w1h = wol + (size_t)768*1152;     __bf16* w1l = w1h + (size_t)2048*768;
        __bf16* w3h = w1l + (size_t)2048*768;     __bf16* w3l = w3h + (size_t)2048*768;
        __bf16* w2h = w3l + (size_t)2048*768;     __bf16* w2l = w2h + (size_t)768*2048;

        CvtBatch8 lb{};
        lb.src[0]=wq + (size_t)l*KDC*DHC; lb.dh[0]=qkh;                   lb.dl[0]=qkl;                   lb.ldv[0]=768;  lb.cols[0]=768;  lb.rowend[0]=576;
        lb.src[1]=wk + (size_t)l*KDC*DHC; lb.dh[1]=qkh+(size_t)576*768;   lb.dl[1]=qkl+(size_t)576*768;   lb.ldv[1]=768;  lb.cols[1]=768;  lb.rowend[1]=1152;
        lb.src[2]=wv + (size_t)l*VDC*DHC; lb.dh[2]=vh;                    lb.dl[2]=vl;                    lb.ldv[2]=768;  lb.cols[2]=768;  lb.rowend[2]=2304;
        lb.src[3]=wg + (size_t)l*VDC*DHC; lb.dh[3]=gh;                    lb.dl[3]=gl_;                   lb.ldv[3]=768;  lb.cols[3]=768;  lb.rowend[3]=3456;
        lb.src[4]=wo + (size_t)l*DHC*VDC; lb.dh[4]=woh;                   lb.dl[4]=wol;                   lb.ldv[4]=1152; lb.cols[4]=1152; lb.rowend[4]=4224;
        lb.src[5]=w1 + (size_t)l*IMC*DHC; lb.dh[5]=w1h;                   lb.dl[5]=w1l;                   lb.ldv[5]=768;  lb.cols[5]=768;  lb.rowend[5]=6272;
        lb.src[6]=w3 + (size_t)l*IMC*DHC; lb.dh[6]=w3h;                   lb.dl[6]=w3l;                   lb.ldv[6]=768;  lb.cols[6]=768;  lb.rowend[6]=8320;
        lb.src[7]=w2 + (size_t)l*DHC*IMC; lb.dh[7]=w2h;                   lb.dl[7]=w2l;                   lb.ldv[7]=2048; lb.cols[7]=2048; lb.rowend[7]=9088;
        hipLaunchKernelGGL(cvt_batch_kernel, dim3(9088), dim3(256), 0, stream, lb, 8);

        hipLaunchKernelGGL(rmsnorm_kernel, dim3(RTOT), dim3(256), 0, stream, X, n1 + l*DHC, XNh, XNl);

        // projections (bf16x2: A = XNh only)
        gemm3(false, XNh, nullptr, qkh, qkl, 768, 1152, 0, BUF1, nullptr, nullptr, nullptr, nullptr, nullptr, nullptr, stream);
        hipLaunchKernelGGL(convsilu_kernel, dim3(9,  RTOT), dim3(64), 0, stream, BUF1,       1152, cq + (size_t)l*KDC*4, QKV,        2304, KDC);
        hipLaunchKernelGGL(convsilu_kernel, dim3(9,  RTOT), dim3(64), 0, stream, BUF1 + 576, 1152, ck + (size_t)l*KDC*4, QKV + 576,  2304, KDC);
        gemm3(false, XNh, nullptr, vh, vl, 768, 1152, 0, BUF1, nullptr, nullptr, nullptr, nullptr, nullptr, nullptr, stream);
        hipLaunchKernelGGL(convsilu_kernel, dim3(18, RTOT), dim3(64), 0, stream, BUF1,       1152, cv + (size_t)l*VDC*4, QKV + 1152, 2304, VDC);
        gemm3(false, XNh, nullptr, gh, gl_, 768, 1152, 0, BUF1, nullptr, nullptr, nullptr, nullptr, nullptr, nullptr, stream);
        hipLaunchKernelGGL(betag_kernel, dim3(RTOT), dim3(256), 0, stream,
                           XNh, XNl, wb + (size_t)l*NHC*DHC, wa + (size_t)l*NHC*DHC,
                           A_log + l*NHC, dt_bias + l*NHC, BETA, DEC);

        hipLaunchKernelGGL(l2norm_kernel, dim3(RTOT), dim3(128), 0, stream, QKV, 2304, 0,   qscale);
        hipLaunchKernelGGL(l2norm_kernel, dim3(RTOT), dim3(128), 0, stream, QKV, 2304, 576, 1.0f);

        // recurrent delta-rule scan (1 wave per seq x head)
        hipLaunchKernelGGL(scan_kernel, dim3(32*NHC), dim3(64), 0, stream, QKV, BETA, DEC, O);

        hipLaunchKernelGGL(opost_kernel, dim3(RTOT), dim3(128), 0, stream, O, BUF1, 1152,
                           onorm + l*DVC, Oh, Ol);
        gemm3(true, Oh, Ol, woh, wol, 1152, 768, 0, X, nullptr, nullptr, X, nullptr, nullptr, nullptr, stream);

        // MLP (bf16x2)
        hipLaunchKernelGGL(rmsnorm_kernel, dim3(RTOT), dim3(256), 0, stream, X, n2 + l*DHC, XNh, XNl);
        gemm3(false, XNh, nullptr, w1h, w1l, 768, 2048, 0, A1f, nullptr, nullptr, nullptr, nullptr, nullptr, nullptr, stream);
        gemm3(false, XNh, nullptr, w3h, w3l, 768, 2048, 2, nullptr, nullptr, nullptr, nullptr, A1h, nullptr, A1f, stream);
        gemm3(false, A1h, nullptr, w2h, w2l, 2048, 768, 0, X, nullptr, nullptr, X, nullptr, nullptr, nullptr, stream);
    }

    // ---- final LN + decoder (bf16x3) ----
    {
        __bf16* dech = WS0;  __bf16* decl = dech + (size_t)1024*768;
        CvtBatch8 db{};
        db.src[0]=dec_w; db.dh[0]=dech; db.dl[0]=decl; db.ldv[0]=768; db.cols[0]=768; db.rowend[0]=1024;
        hipLaunchKernelGGL(cvt_batch_kernel, dim3(1024), dim3(256), 0, stream, db, 1);
        hipLaunchKernelGGL(layernorm_kernel, dim3(RTOT), dim3(256), 0, stream, X, ln_w, ln_b, XNh, XNl);
        gemm3(true, XNh, XNl, dech, decl, 768, 1024, 0, (float*)d_out, dec_b, nullptr, z, nullptr, nullptr, nullptr, stream);
    }
}

// Round 11
// 5321.260 us; speedup vs baseline: 2.4474x; 1.0891x over previous
//
#include <hip/hip_runtime.h>
#include <math.h>

// ---- problem constants ----
#define RTOT 8192   // B*T*N token rows
#define SEQL 256    // tokens per folded sequence
#define DHC 768
#define KDC 576
#define VDC 1152
#define IMC 2048
#define NHC 12
#define DKC 48
#define DVC 96
#define NLAY 5

typedef float f4 __attribute__((ext_vector_type(4)));
typedef __bf16 v8bf __attribute__((ext_vector_type(8)));

__device__ __forceinline__ float sigmoidf_(float x){ return 1.0f/(1.0f+expf(-x)); }
__device__ __forceinline__ float siluf_(float x){ return x/(1.0f+expf(-x)); }

__device__ __forceinline__ void gl16(const void* g, void* l) {
    __builtin_amdgcn_global_load_lds((const __attribute__((address_space(1))) void*)g,
                                     (__attribute__((address_space(3))) void*)l, 16, 0, 0);
}
#define MFMA_BF16(a,b,c) __builtin_amdgcn_mfma_f32_16x16x32_bf16((a),(b),(c),0,0,0)

// =====================================================================
// bf16x3 / bf16x2 MFMA GEMM: C[M=8192, N=ldc] = A[M,K] @ W[N,K]^T.
// HASAL=true : acc += Al*Bh + Ah*Bl + Ah*Bh  (bf16x3, ~fp32)
// HASAL=false: acc += Ah*Bl + Ah*Bh          (bf16x2, ~2^-9 rel err)
// (proven r7/r10: absmax 0.0356 — DO NOT TOUCH)
// =====================================================================
template<bool HASAL>
__global__ __launch_bounds__(256)
void gemm3_kernel(const __bf16* __restrict__ Ah, const __bf16* __restrict__ Al,
                  const __bf16* __restrict__ Wh, const __bf16* __restrict__ Wl,
                  int K, int ldc, int mode,
                  float* Cf, const float* bias, const float* bias2, const float* res,
                  __bf16* Ch, __bf16* Cl, const float* aux)
{
    __shared__ __bf16 sAh[128*32], sBh[128*32], sBl[128*32];
    __shared__ __bf16 sAl[HASAL ? 128*32 : 16];
    const int tid  = threadIdx.x;
    const int m0   = blockIdx.y * 128, n0 = blockIdx.x * 128;
    const int lane = tid & 63, wv = tid >> 6;
    const int wm   = (wv & 1) * 64, wn = (wv >> 1) * 64;

    const int o0 = tid * 16, o1 = o0 + 4096;
    const int r0 = o0 >> 6, s0 = (o0 >> 4) & 3;
    const int r1 = o1 >> 6, s1 = (o1 >> 4) & 3;
    const int k0 = (s0 ^ ((r0 >> 1) & 3)) * 8;
    const int k1 = (s1 ^ ((r1 >> 1) & 3)) * 8;

    const __bf16* gA0h = Ah + (size_t)(m0 + r0) * K + k0;
    const __bf16* gA1h = Ah + (size_t)(m0 + r1) * K + k1;
    const __bf16* gA0l = HASAL ? (Al + (size_t)(m0 + r0) * K + k0) : nullptr;
    const __bf16* gA1l = HASAL ? (Al + (size_t)(m0 + r1) * K + k1) : nullptr;
    const __bf16* gB0h = Wh + (size_t)(n0 + r0) * K + k0;
    const __bf16* gB1h = Wh + (size_t)(n0 + r1) * K + k1;
    const __bf16* gB0l = Wl + (size_t)(n0 + r0) * K + k0;
    const __bf16* gB1l = Wl + (size_t)(n0 + r1) * K + k1;

    const int fr = lane & 15, g8 = lane >> 4;
    int aoff[4], boff[4];
    #pragma unroll
    for (int f = 0; f < 4; ++f) {
        int ra = wm + f*16 + fr;
        aoff[f] = ra*32 + (g8 ^ ((ra >> 1) & 3)) * 8;
        int rb = wn + f*16 + fr;
        boff[f] = rb*32 + (g8 ^ ((rb >> 1) & 3)) * 8;
    }

    f4 acc[4][4];
    const f4 zero4 = {0.f, 0.f, 0.f, 0.f};
    #pragma unroll
    for (int i = 0; i < 4; ++i)
        #pragma unroll
        for (int j = 0; j < 4; ++j) acc[i][j] = zero4;

    for (int kt = 0; kt < K; kt += 32) {
        gl16(gA0h + kt, (char*)sAh + o0);
        gl16(gA1h + kt, (char*)sAh + o1);
        if constexpr (HASAL) {
            gl16(gA0l + kt, (char*)sAl + o0);
            gl16(gA1l + kt, (char*)sAl + o1);
        }
        gl16(gB0h + kt, (char*)sBh + o0);
        gl16(gB1h + kt, (char*)sBh + o1);
        gl16(gB0l + kt, (char*)sBl + o0);
        gl16(gB1l + kt, (char*)sBl + o1);
        __syncthreads();

        v8bf bhv[4], blv[4];
        #pragma unroll
        for (int f = 0; f < 4; ++f) {
            bhv[f] = *(const v8bf*)(sBh + boff[f]);
            blv[f] = *(const v8bf*)(sBl + boff[f]);
        }
        #pragma unroll
        for (int i = 0; i < 4; ++i) {
            v8bf ahv = *(const v8bf*)(sAh + aoff[i]);
            v8bf alv;
            if constexpr (HASAL) alv = *(const v8bf*)(sAl + aoff[i]);
            #pragma unroll
            for (int j = 0; j < 4; ++j) {
                f4 t = acc[i][j];
                if constexpr (HASAL) t = MFMA_BF16(alv, bhv[j], t);   // Alo*Bhi
                t = MFMA_BF16(ahv, blv[j], t);                        // Ahi*Blo
                acc[i][j] = MFMA_BF16(ahv, bhv[j], t);                // Ahi*Bhi
            }
        }
        __syncthreads();
    }

    const int rb4 = (lane >> 4) * 4;
    #pragma unroll
    for (int i = 0; i < 4; ++i) {
        #pragma unroll
        for (int jf = 0; jf < 4; ++jf) {
            int col = n0 + wn + jf*16 + fr;
            #pragma unroll
            for (int j = 0; j < 4; ++j) {
                int row = m0 + wm + i*16 + rb4 + j;
                size_t idx = (size_t)row * ldc + col;
                float v = acc[i][jf][j];
                if (bias)  v += bias[col];
                if (bias2) v += bias2[(size_t)(row >> 8) * ldc + col];
                if (res)   v += res[idx];
                if (mode == 2) v = siluf_(aux[idx]) * v;
                if (mode == 0) {
                    Cf[idx] = v;
                } else {
                    __bf16 h = (__bf16)v;
                    Ch[idx] = h;
                    if (Cl) Cl[idx] = (__bf16)(v - (float)h);
                }
            }
        }
    }
}

// =====================================================================
// batched fp32 -> (hi,lo) bf16 conversion: up to 8 jobs in one launch
// =====================================================================
struct CvtBatch8 {
    const float* src[8];
    __bf16* dh[8];
    __bf16* dl[8];
    int ldv[8];
    int cols[8];
    int rowend[8];
};

__global__ __launch_bounds__(256)
void cvt_batch_kernel(CvtBatch8 b, int njobs)
{
    int r = blockIdx.x;
    int j = 0;
    while (j < njobs - 1 && r >= b.rowend[j]) ++j;
    int row0 = (j == 0) ? 0 : b.rowend[j-1];
    int lr = r - row0;
    const float* s = b.src[j] + (size_t)lr * b.ldv[j];
    __bf16* ph = b.dh[j] + (size_t)lr * b.cols[j];
    __bf16* pl = b.dl[j] + (size_t)lr * b.cols[j];
    int cols = b.cols[j];
    for (int c = threadIdx.x; c < cols; c += 256) {
        float v = s[c];
        __bf16 hh = (__bf16)v;
        ph[c] = hh;
        pl[c] = (__bf16)(v - (float)hh);
    }
}

// =====================================================================
__global__ __launch_bounds__(256)
void bias2_kernel(const float* __restrict__ actions, const float* __restrict__ ap_w,
                  const float* __restrict__ ap_b, const float* __restrict__ temb,
                  float* __restrict__ B2)
{
    int bt = blockIdx.x;
    int t  = bt & 7;
    float a0 = actions[bt*2], a1 = actions[bt*2+1];
    for (int c = threadIdx.x; c < DHC; c += 256)
        B2[bt*DHC + c] = ap_b[c] + temb[t*DHC + c] + a0*ap_w[c*770 + 768] + a1*ap_w[c*770 + 769];
}

// =====================================================================
__global__ __launch_bounds__(256)
void rmsnorm_kernel(const float* __restrict__ X, const float* __restrict__ w,
                    __bf16* __restrict__ Yh, __bf16* __restrict__ Yl)
{
    int row = blockIdx.x, tid = threadIdx.x;
    const float* xr = X + (size_t)row*DHC;
    float v0 = xr[tid], v1 = xr[tid+256], v2 = xr[tid+512];
    __shared__ float red[256];
    red[tid] = v0*v0 + v1*v1 + v2*v2;
    __syncthreads();
    for (int s = 128; s; s >>= 1) { if (tid < s) red[tid] += red[tid+s]; __syncthreads(); }
    float r = 1.0f/sqrtf(red[0]/768.0f + 1e-6f);
    float y0 = v0*r*w[tid], y1 = v1*r*w[tid+256], y2 = v2*r*w[tid+512];
    __bf16* ph = Yh + (size_t)row*DHC;
    __bf16* pl = Yl + (size_t)row*DHC;
    __bf16 h0 = (__bf16)y0, h1 = (__bf16)y1, h2 = (__bf16)y2;
    ph[tid] = h0;     pl[tid]     = (__bf16)(y0 - (float)h0);
    ph[tid+256] = h1; pl[tid+256] = (__bf16)(y1 - (float)h1);
    ph[tid+512] = h2; pl[tid+512] = (__bf16)(y2 - (float)h2);
}

// =====================================================================
__global__ __launch_bounds__(256)
void layernorm_kernel(const float* __restrict__ X, const float* __restrict__ w,
                      const float* __restrict__ b, __bf16* __restrict__ Yh,
                      __bf16* __restrict__ Yl)
{
    int row = blockIdx.x, tid = threadIdx.x;
    const float* xr = X + (size_t)row*DHC;
    float v0 = xr[tid], v1 = xr[tid+256], v2 = xr[tid+512];
    __shared__ float rs[256], rs2[256];
    rs[tid]  = v0+v1+v2;
    rs2[tid] = v0*v0+v1*v1+v2*v2;
    __syncthreads();
    for (int s = 128; s; s >>= 1) { if (tid < s) { rs[tid]+=rs[tid+s]; rs2[tid]+=rs2[tid+s]; } __syncthreads(); }
    float mu  = rs[0]/768.0f;
    float var = rs2[0]/768.0f - mu*mu;
    float r = 1.0f/sqrtf(var + 1e-5f);
    float y0 = (v0-mu)*r*w[tid]     + b[tid];
    float y1 = (v1-mu)*r*w[tid+256] + b[tid+256];
    float y2 = (v2-mu)*r*w[tid+512] + b[tid+512];
    __bf16* ph = Yh + (size_t)row*DHC;
    __bf16* pl = Yl + (size_t)row*DHC;
    __bf16 h0 = (__bf16)y0, h1 = (__bf16)y1, h2 = (__bf16)y2;
    ph[tid] = h0;     pl[tid]     = (__bf16)(y0 - (float)h0);
    ph[tid+256] = h1; pl[tid+256] = (__bf16)(y1 - (float)h1);
    ph[tid+512] = h2; pl[tid+512] = (__bf16)(y2 - (float)h2);
}

// =====================================================================
__global__ __launch_bounds__(64)
void convsilu_kernel(const float* __restrict__ P, int ldp, const float* __restrict__ cw,
                     float* __restrict__ Y, int ldd, int C)
{
    int c = blockIdx.x*64 + threadIdx.x;
    if (c >= C) return;
    int r = blockIdx.y;
    int t = r & (SEQL-1);
    float acc = P[(size_t)r*ldp + c] * cw[c*4+3];
    if (t >= 1) acc += P[(size_t)(r-1)*ldp + c] * cw[c*4+2];
    if (t >= 2) acc += P[(size_t)(r-2)*ldp + c] * cw[c*4+1];
    if (t >= 3) acc += P[(size_t)(r-3)*ldp + c] * cw[c*4+0];
    Y[(size_t)r*ldd + c] = siluf_(acc);
}

// =====================================================================
__global__ __launch_bounds__(128)
void l2norm_kernel(float* __restrict__ X, int ld, int col0, float scale)
{
    int row = blockIdx.x;
    int wave = threadIdx.x >> 6, lane = threadIdx.x & 63;
    #pragma unroll
    for (int i = 0; i < 6; ++i) {
        int h = wave*6 + i;
        size_t base = (size_t)row*ld + col0 + h*DKC;
        float v = (lane < DKC) ? X[base + lane] : 0.f;
        float ss = v*v;
        for (int off = 32; off; off >>= 1) ss += __shfl_down(ss, off);
        ss = __shfl(ss, 0);
        float r = scale / sqrtf(ss + 1e-6f);
        if (lane < DKC) X[base + lane] = v*r;
    }
}

// =====================================================================
__global__ __launch_bounds__(256)
void betag_kernel(const __bf16* __restrict__ XNh, const __bf16* __restrict__ XNl,
                  const float* __restrict__ wb, const float* __restrict__ wa,
                  const float* __restrict__ Alog, const float* __restrict__ dtb,
                  float* __restrict__ Beta, float* __restrict__ Dec)
{
    int row = blockIdx.x, tid = threadIdx.x;
    __shared__ float sx[DHC];
    for (int i = tid; i < DHC; i += 256)
        sx[i] = (float)XNh[(size_t)row*DHC + i] + (float)XNl[(size_t)row*DHC + i];
    __syncthreads();
    int wave = tid >> 6, lane = tid & 63;
    for (int d = 0; d < 6; ++d) {
        int out = wave*6 + d;
        const float* wr = (out < NHC) ? (wb + out*DHC) : (wa + (out-NHC)*DHC);
        float acc = 0.f;
        for (int j = lane; j < DHC; j += 64) acc += sx[j]*wr[j];
        for (int off = 32; off; off >>= 1) acc += __shfl_down(acc, off);
        if (lane == 0) {
            if (out < NHC) {
                Beta[(size_t)row*NHC + out] = sigmoidf_(acc);
            } else {
                int h = out - NHC;
                float sp = acc + dtb[h];
                sp = (sp > 20.f) ? sp : log1pf(expf(sp));
                Dec[(size_t)row*NHC + h] = expf(-expf(Alog[h]) * sp);
            }
        }
    }
}

// =====================================================================
// gated delta-rule scan — 6 INDEPENDENT waves per (seq,head), no LDS,
// no barriers, all data register-prefetched from global (depth 4).
// Wave = 16 v-cols x 4 k-groups (lane = colInChunk*4 + rg), identical
// work assignment and reduction tree to the round-8 kernel
// (bit-identical numerics). Grid 2304 waves = 2.25/SIMD for TLP.
// =====================================================================
struct Tok { float k[12]; float q[12]; float v, d, b; };

__device__ __forceinline__ void tok_load(Tok& T, const float* kp, const float* qp,
                                         const float* vp, const float* dp,
                                         const float* bp, int t)
{
    size_t ro = (size_t)t * 2304;
    *(float4*)&T.k[0] = *(const float4*)(kp + ro);
    *(float4*)&T.k[4] = *(const float4*)(kp + ro + 4);
    *(float4*)&T.k[8] = *(const float4*)(kp + ro + 8);
    *(float4*)&T.q[0] = *(const float4*)(qp + ro);
    *(float4*)&T.q[4] = *(const float4*)(qp + ro + 4);
    *(float4*)&T.q[8] = *(const float4*)(qp + ro + 8);
    T.v = vp[ro];
    T.d = dp[(size_t)t * NHC];
    T.b = bp[(size_t)t * NHC];
}

__device__ __forceinline__ void scan_step(const Tok& Tk, float S[12], int rg,
                                          float* op, int T)
{
    float dec = Tk.d, beta = Tk.b;
    float pv0 = 0.f, pv1 = 0.f;
    #pragma unroll
    for (int i = 0; i < 12; i += 2) {
        S[i]   *= dec; pv0 += Tk.k[i]  * S[i];
        S[i+1] *= dec; pv1 += Tk.k[i+1]* S[i+1];
    }
    float pv = pv0 + pv1;
    pv += __shfl_xor(pv, 1); pv += __shfl_xor(pv, 2);
    float dvv = beta * (Tk.v - pv);
    float po0 = 0.f, po1 = 0.f;
    #pragma unroll
    for (int i = 0; i < 12; i += 2) {
        S[i]   += Tk.k[i]  * dvv; po0 += Tk.q[i]  * S[i];
        S[i+1] += Tk.k[i+1]* dvv; po1 += Tk.q[i+1]* S[i+1];
    }
    float po = po0 + po1;
    po += __shfl_xor(po, 1); po += __shfl_xor(po, 2);
    if (rg == 0) op[(size_t)T * VDC] = po;
}

__global__ __launch_bounds__(64)
void scan_kernel(const float* __restrict__ QKV, const float* __restrict__ Beta,
                 const float* __restrict__ Dec, float* __restrict__ O)
{
    int bid   = blockIdx.x;            // 2304 = 32 seq x 12 head x 6 chunk
    int chunk = bid % 6;
    int sh    = bid / 6;
    int seq = sh / NHC, h = sh % NHC;
    int lane = threadIdx.x;
    int col = chunk*16 + (lane >> 2);  // 0..95
    int rg  = lane & 3;

    const float* rowb = QKV + (size_t)seq*SEQL*2304;
    const float* kp = rowb + 576  + h*DKC + rg*12;
    const float* qp = rowb +        h*DKC + rg*12;
    const float* vp = rowb + 1152 + h*DVC + col;
    const float* dp = Dec  + (size_t)seq*SEQL*NHC + h;
    const float* bp = Beta + (size_t)seq*SEQL*NHC + h;
    float* op = O + (size_t)seq*SEQL*VDC + h*DVC + col;

    float S[12];
    #pragma unroll
    for (int i = 0; i < 12; ++i) S[i] = 0.f;

    Tok A, B, C, D;
    tok_load(A, kp, qp, vp, dp, bp, 0);
    tok_load(B, kp, qp, vp, dp, bp, 1);
    tok_load(C, kp, qp, vp, dp, bp, 2);
    tok_load(D, kp, qp, vp, dp, bp, 3);

    for (int t = 0; t < SEQL; t += 4) {
        scan_step(A, S, rg, op, t);
        if (t + 4 < SEQL) tok_load(A, kp, qp, vp, dp, bp, t + 4);
        scan_step(B, S, rg, op, t + 1);
        if (t + 5 < SEQL) tok_load(B, kp, qp, vp, dp, bp, t + 5);
        scan_step(C, S, rg, op, t + 2);
        if (t + 6 < SEQL) tok_load(C, kp, qp, vp, dp, bp, t + 6);
        scan_step(D, S, rg, op, t + 3);
        if (t + 7 < SEQL) tok_load(D, kp, qp, vp, dp, bp, t + 7);
    }
}

// =====================================================================
__global__ __launch_bounds__(128)
void opost_kernel(const float* __restrict__ O, const float* __restrict__ G, int ldg,
                  const float* __restrict__ onorm, __bf16* __restrict__ Oh,
                  __bf16* __restrict__ Ol)
{
    int row = blockIdx.x;
    int wave = threadIdx.x >> 6, lane = threadIdx.x & 63;
    #pragma unroll
    for (int i = 0; i < 6; ++i) {
        int h = wave*6 + i;
        size_t baseO = (size_t)row*VDC + h*DVC;
        size_t baseG = (size_t)row*ldg + h*DVC;
        float a = O[baseO + lane];
        float c = (lane < 32) ? O[baseO + 64 + lane] : 0.f;
        float ss = a*a + c*c;
        for (int off = 32; off; off >>= 1) ss += __shfl_down(ss, off);
        ss = __shfl(ss, 0);
        float r = 1.0f/sqrtf(ss/96.0f + 1e-6f);
        float ga = G[baseG + lane];
        float v0 = a*r*onorm[lane]*ga*sigmoidf_(ga);
        { __bf16 hh = (__bf16)v0; Oh[baseO+lane] = hh; Ol[baseO+lane] = (__bf16)(v0 - (float)hh); }
        if (lane < 32) {
            float gb = G[baseG + 64 + lane];
            float v1 = c*r*onorm[64+lane]*gb*sigmoidf_(gb);
            __bf16 hh = (__bf16)v1; Oh[baseO+64+lane] = hh; Ol[baseO+64+lane] = (__bf16)(v1 - (float)hh);
        }
    }
}

// =====================================================================
static inline void gemm3(bool hasAl,
                         const __bf16* Ah, const __bf16* Al, const __bf16* Wh, const __bf16* Wl,
                         int K, int ldc, int mode, float* Cf, const float* bias,
                         const float* bias2, const float* res, __bf16* Ch, __bf16* Cl,
                         const float* aux, hipStream_t s)
{
    dim3 grid(ldc/128, RTOT/128);
    if (hasAl)
        hipLaunchKernelGGL(gemm3_kernel<true>,  grid, dim3(256), 0, s, Ah, Al, Wh, Wl, K, ldc, mode,
                           Cf, bias, bias2, res, Ch, Cl, aux);
    else
        hipLaunchKernelGGL(gemm3_kernel<false>, grid, dim3(256), 0, s, Ah, Al, Wh, Wl, K, ldc, mode,
                           Cf, bias, bias2, res, Ch, Cl, aux);
}

extern "C" void kernel_launch(void* const* d_in, const int* in_sizes, int n_in,
                              void* d_out, int out_size, void* d_ws, size_t ws_size,
                              hipStream_t stream)
{
    const float* z       = (const float*)d_in[0];
    const float* actions = (const float*)d_in[1];
    const float* enc_w   = (const float*)d_in[2];
    const float* enc_b   = (const float*)d_in[3];
    const float* ap_w    = (const float*)d_in[4];
    const float* ap_b    = (const float*)d_in[5];
    const float* temb    = (const float*)d_in[6];
    const float* ln_w    = (const float*)d_in[7];
    const float* ln_b    = (const float*)d_in[8];
    const float* dec_w   = (const float*)d_in[9];
    const float* dec_b   = (const float*)d_in[10];
    const float* n1      = (const float*)d_in[11];
    const float* n2      = (const float*)d_in[12];
    const float* wq      = (const float*)d_in[13];
    const float* cq      = (const float*)d_in[14];
    const float* wk      = (const float*)d_in[15];
    const float* ck      = (const float*)d_in[16];
    const float* wv      = (const float*)d_in[17];
    const float* cv      = (const float*)d_in[18];
    const float* wb      = (const float*)d_in[19];
    const float* wa      = (const float*)d_in[20];
    const float* A_log   = (const float*)d_in[21];
    const float* dt_bias = (const float*)d_in[22];
    const float* wg      = (const float*)d_in[23];
    const float* onorm   = (const float*)d_in[24];
    const float* wo      = (const float*)d_in[25];
    const float* w1      = (const float*)d_in[26];
    const float* w2      = (const float*)d_in[27];
    const float* w3      = (const float*)d_in[28];

    const size_t R = RTOT;
    const float qscale = 0.14433756729740643f;   // 48^-0.5

    // ---- workspace layout (unchanged; 235.2 MB) ----
    float* X    = (float*)d_ws;
    float* BUF1 = X    + 768*R;
    float* O    = BUF1 + 1152*R;
    float* QKV  = O    + 1152*R;
    float* BETA = QKV  + 2304*R;
    float* DEC  = BETA + 12*R;
    float* TMP  = DEC  + 12*R;
    __bf16* XNh = (__bf16*)(TMP + 32*768);
    __bf16* XNl = XNh + 768*R;
    __bf16* WS0 = XNl + 768*R;

    const size_t need = (size_t)(768+1152+1152+2304+24)*R*4 + 32*768*4
                      + ((size_t)1536*R + 16515072)*2;
    if (ws_size < need) return;

    // aliases
    __bf16* zh  = (__bf16*)QKV;
    __bf16* zl  = zh + 1024*R;
    __bf16* Oh  = (__bf16*)QKV;
    __bf16* Ol  = Oh + 1152*R;
    float*  A1f = QKV;
    __bf16* A1h = (__bf16*)BUF1;

    // ---- encoder (bf16x3) ----
    {
        __bf16* ench = WS0;                       __bf16* encl = ench + (size_t)768*1024;
        __bf16* aph  = encl + (size_t)768*1024;   __bf16* apl  = aph  + (size_t)768*768;

        CvtBatch8 eb{};
        eb.src[0]=z;     eb.dh[0]=zh;   eb.dl[0]=zl;   eb.ldv[0]=1024; eb.cols[0]=1024; eb.rowend[0]=8192;
        eb.src[1]=enc_w; eb.dh[1]=ench; eb.dl[1]=encl; eb.ldv[1]=1024; eb.cols[1]=1024; eb.rowend[1]=8960;
        eb.src[2]=ap_w;  eb.dh[2]=aph;  eb.dl[2]=apl;  eb.ldv[2]=770;  eb.cols[2]=768;  eb.rowend[2]=9728;
        hipLaunchKernelGGL(cvt_batch_kernel, dim3(9728), dim3(256), 0, stream, eb, 3);

        hipLaunchKernelGGL(bias2_kernel, dim3(32), dim3(256), 0, stream, actions, ap_w, ap_b, temb, TMP);
        gemm3(true, zh, zl, ench, encl, 1024, 768, 1, nullptr, enc_b, nullptr, nullptr, XNh, XNl, nullptr, stream);
        gemm3(true, XNh, XNl, aph, apl, 768, 768, 0, X, nullptr, TMP, nullptr, nullptr, nullptr, nullptr, stream);
    }

    // ---- layers ----
    for (int l = 0; l < NLAY; ++l) {
        __bf16* qkh = WS0;                        __bf16* qkl = qkh + (size_t)1152*768;
        __bf16* vh  = qkl + (size_t)1152*768;     __bf16* vl  = vh  + (size_t)1152*768;
        __bf16* gh  = vl  + (size_t)1152*768;     __bf16* gl_ = gh  + (size_t)1152*768;
        __bf16* woh = gl_ + (size_t)1152*768;     __bf16* wol = woh + (size_t)768*1152;
        __bf16* w1h = wol + (size_t)768*1152;     __bf16* w1l = w1h + (size_t)2048*768;
        __bf16* w3h = w1l + (size_t)2048*768;     __bf16* w3l = w3h + (size_t)2048*768;
        __bf16* w2h = w3l + (size_t)2048*768;     __bf16* w2l = w2h + (size_t)768*2048;

        CvtBatch8 lb{};
        lb.src[0]=wq + (size_t)l*KDC*DHC; lb.dh[0]=qkh;                   lb.dl[0]=qkl;                   lb.ldv[0]=768;  lb.cols[0]=768;  lb.rowend[0]=576;
        lb.src[1]=wk + (size_t)l*KDC*DHC; lb.dh[1]=qkh+(size_t)576*768;   lb.dl[1]=qkl+(size_t)576*768;   lb.ldv[1]=768;  lb.cols[1]=768;  lb.rowend[1]=1152;
        lb.src[2]=wv + (size_t)l*VDC*DHC; lb.dh[2]=vh;                    lb.dl[2]=vl;                    lb.ldv[2]=768;  lb.cols[2]=768;  lb.rowend[2]=2304;
        lb.src[3]=wg + (size_t)l*VDC*DHC; lb.dh[3]=gh;                    lb.dl[3]=gl_;                   lb.ldv[3]=768;  lb.cols[3]=768;  lb.rowend[3]=3456;
        lb.src[4]=wo + (size_t)l*DHC*VDC; lb.dh[4]=woh;                   lb.dl[4]=wol;                   lb.ldv[4]=1152; lb.cols[4]=1152; lb.rowend[4]=4224;
        lb.src[5]=w1 + (size_t)l*IMC*DHC; lb.dh[5]=w1h;                   lb.dl[5]=w1l;                   lb.ldv[5]=768;  lb.cols[5]=768;  lb.rowend[5]=6272;
        lb.src[6]=w3 + (size_t)l*IMC*DHC; lb.dh[6]=w3h;                   lb.dl[6]=w3l;                   lb.ldv[6]=768;  lb.cols[6]=768;  lb.rowend[6]=8320;
        lb.src[7]=w2 + (size_t)l*DHC*IMC; lb.dh[7]=w2h;                   lb.dl[7]=w2l;                   lb.ldv[7]=2048; lb.cols[7]=2048; lb.rowend[7]=9088;
        hipLaunchKernelGGL(cvt_batch_kernel, dim3(9088), dim3(256), 0, stream, lb, 8);

        hipLaunchKernelGGL(rmsnorm_kernel, dim3(RTOT), dim3(256), 0, stream, X, n1 + l*DHC, XNh, XNl);

        // projections (bf16x2: A = XNh only)
        gemm3(false, XNh, nullptr, qkh, qkl, 768, 1152, 0, BUF1, nullptr, nullptr, nullptr, nullptr, nullptr, nullptr, stream);
        hipLaunchKernelGGL(convsilu_kernel, dim3(9,  RTOT), dim3(64), 0, stream, BUF1,       1152, cq + (size_t)l*KDC*4, QKV,        2304, KDC);
        hipLaunchKernelGGL(convsilu_kernel, dim3(9,  RTOT), dim3(64), 0, stream, BUF1 + 576, 1152, ck + (size_t)l*KDC*4, QKV + 576,  2304, KDC);
        gemm3(false, XNh, nullptr, vh, vl, 768, 1152, 0, BUF1, nullptr, nullptr, nullptr, nullptr, nullptr, nullptr, stream);
        hipLaunchKernelGGL(convsilu_kernel, dim3(18, RTOT), dim3(64), 0, stream, BUF1,       1152, cv + (size_t)l*VDC*4, QKV + 1152, 2304, VDC);
        gemm3(false, XNh, nullptr, gh, gl_, 768, 1152, 0, BUF1, nullptr, nullptr, nullptr, nullptr, nullptr, nullptr, stream);
        hipLaunchKernelGGL(betag_kernel, dim3(RTOT), dim3(256), 0, stream,
                           XNh, XNl, wb + (size_t)l*NHC*DHC, wa + (size_t)l*NHC*DHC,
                           A_log + l*NHC, dt_bias + l*NHC, BETA, DEC);

        hipLaunchKernelGGL(l2norm_kernel, dim3(RTOT), dim3(128), 0, stream, QKV, 2304, 0,   qscale);
        hipLaunchKernelGGL(l2norm_kernel, dim3(RTOT), dim3(128), 0, stream, QKV, 2304, 576, 1.0f);

        // recurrent delta-rule scan (6 independent waves per seq x head)
        hipLaunchKernelGGL(scan_kernel, dim3(32*NHC*6), dim3(64), 0, stream, QKV, BETA, DEC, O);

        hipLaunchKernelGGL(opost_kernel, dim3(RTOT), dim3(128), 0, stream, O, BUF1, 1152,
                           onorm + l*DVC, Oh, Ol);
        gemm3(true, Oh, Ol, woh, wol, 1152, 768, 0, X, nullptr, nullptr, X, nullptr, nullptr, nullptr, stream);

        // MLP (bf16x2)
        hipLaunchKernelGGL(rmsnorm_kernel, dim3(RTOT), dim3(256), 0, stream, X, n2 + l*DHC, XNh, XNl);
        gemm3(false, XNh, nullptr, w1h, w1l, 768, 2048, 0, A1f, nullptr, nullptr, nullptr, nullptr, nullptr, nullptr, stream);
        gemm3(false, XNh, nullptr, w3h, w3l, 768, 2048, 2, nullptr, nullptr, nullptr, nullptr, A1h, nullptr, A1f, stream);
        gemm3(false, A1h, nullptr, w2h, w2l, 2048, 768, 0, X, nullptr, nullptr, X, nullptr, nullptr, nullptr, stream);
    }

    // ---- final LN + decoder (bf16x3) ----
    {
        __bf16* dech = WS0;  __bf16* decl = dech + (size_t)1024*768;
        CvtBatch8 db{};
        db.src[0]=dec_w; db.dh[0]=dech; db.dl[0]=decl; db.ldv[0]=768; db.cols[0]=768; db.rowend[0]=1024;
        hipLaunchKernelGGL(cvt_batch_kernel, dim3(1024), dim3(256), 0, stream, db, 1);
        hipLaunchKernelGGL(layernorm_kernel, dim3(RTOT), dim3(256), 0, stream, X, ln_w, ln_b, XNh, XNl);
        gemm3(true, XNh, XNl, dech, decl, 768, 1024, 0, (float*)d_out, dec_b, nullptr, z, nullptr, nullptr, nullptr, stream);
    }
}